// Round 1
// baseline (1334.338 us; speedup 1.0000x reference)
//
#include <hip/hip_runtime.h>
#include <cstdint>
#include <cmath>

typedef unsigned short u16;
typedef __bf16 bf16x8 __attribute__((ext_vector_type(8)));
typedef float f32x4 __attribute__((ext_vector_type(4)));

__device__ __forceinline__ u16 bf16_rne(float v) {
    union { float f; uint32_t u; } a; a.f = v;
    uint32_t r = a.u + 0x7fffu + ((a.u >> 16) & 1u);
    return (u16)(r >> 16);
}
__device__ __forceinline__ float bf16_to_f(u16 h) {
    union { uint32_t u; float f; } a; a.u = ((uint32_t)h) << 16;
    return a.f;
}

// Shapes: B=16, Cb=256, H=W=128 -> h2=w2=64. hid=512. Cs=512.
// hf tokens: 32x32=1024/batch/band, 3 bands -> 49152 tokens, dim 256.

// ---------------------------------------------------------------- K1: Haar |band| 2x2-mean tokens
// z layout: [band(3)][b*256+c][1024 tokens], token t = py*32+px
__global__ __launch_bounds__(256)
void k_haar_tokens(const float* __restrict__ xb, float* __restrict__ z)
{
    const int bc = blockIdx.x;            // b*256 + c
    const int px  = threadIdx.x & 31;
    const int py0 = threadIdx.x >> 5;     // [0,8)
    const float* base = xb + (size_t)bc * (128 * 128);
#pragma unroll
    for (int s = 0; s < 4; ++s) {
        const int py = py0 + 8 * s;       // [0,32)
        const float* p = base + (4 * py) * 128 + 4 * px;
        const float4 r0 = *(const float4*)(p);
        const float4 r1 = *(const float4*)(p + 128);
        const float4 r2 = *(const float4*)(p + 256);
        const float4 r3 = *(const float4*)(p + 384);
        float zh = 0.f, zv = 0.f, zd = 0.f;
        {
            const float p00 = r0.x, p01 = r0.y, p10 = r1.x, p11 = r1.y;
            zh += fabsf(p00 - p01 + p10 - p11);
            zv += fabsf(p00 + p01 - p10 - p11);
            zd += fabsf(p00 - p01 - p10 + p11);
        }
        {
            const float p00 = r0.z, p01 = r0.w, p10 = r1.z, p11 = r1.w;
            zh += fabsf(p00 - p01 + p10 - p11);
            zv += fabsf(p00 + p01 - p10 - p11);
            zd += fabsf(p00 - p01 - p10 + p11);
        }
        {
            const float p00 = r2.x, p01 = r2.y, p10 = r3.x, p11 = r3.y;
            zh += fabsf(p00 - p01 + p10 - p11);
            zv += fabsf(p00 + p01 - p10 - p11);
            zd += fabsf(p00 - p01 - p10 + p11);
        }
        {
            const float p00 = r2.z, p01 = r2.w, p10 = r3.z, p11 = r3.w;
            zh += fabsf(p00 - p01 + p10 - p11);
            zv += fabsf(p00 + p01 - p10 - p11);
            zd += fabsf(p00 - p01 - p10 + p11);
        }
        const float sc = 0.0625f;
        const int t = py * 32 + px;
        z[(size_t)(0 * 4096 + bc) * 1024 + t] = zh * sc;
        z[(size_t)(1 * 4096 + bc) * 1024 + t] = zv * sc;
        z[(size_t)(2 * 4096 + bc) * 1024 + t] = zd * sc;
    }
}

// ---------------------------------------------------------------- K2: 4x4 mean pool of x_small
__global__ __launch_bounds__(256)
void k_pool_small(const float* __restrict__ xs, float* __restrict__ sp)
{
    const int bs = blockIdx.x;            // b*512 + s
    const int px = threadIdx.x & 15;
    const int py = threadIdx.x >> 4;
    const float* p = xs + (size_t)bs * 4096 + (4 * py) * 64 + 4 * px;
    float s = 0.f;
#pragma unroll
    for (int r = 0; r < 4; ++r) {
        const float4 v = *(const float4*)(p + 64 * r);
        s += v.x + v.y + v.z + v.w;
    }
    sp[(size_t)bs * 256 + threadIdx.x] = s * 0.0625f;
}

// ---------------------------------------------------------------- K_prep: split W1/W2 into bf16 hi/lo MFMA-fragment layout
// W1f: [kt(8)][kg(4)][col(512)][e(8)], element = W1[kt*32+kg*8+e][col]
// W2f: [k2t(16)][kg(4)][col(256)][e(8)], element = W2[k2t*32+kg*8+e][col]
__global__ __launch_bounds__(256)
void k_prep(const float* __restrict__ w1, const float* __restrict__ w2,
            u16* __restrict__ w1fh, u16* __restrict__ w1fl,
            u16* __restrict__ w2fh, u16* __restrict__ w2fl)
{
    const int bid = blockIdx.x;
    if (bid < 256) {
        const int k = bid;
        const int kt = k >> 5, kg = (k >> 3) & 3, e = k & 7;
        for (int col = threadIdx.x; col < 512; col += 256) {
            const float v = w1[(size_t)k * 512 + col];
            const u16 h = bf16_rne(v);
            const u16 lo = bf16_rne(v - bf16_to_f(h));
            const size_t idx = ((size_t)((kt * 4 + kg) * 512) + col) * 8 + e;
            w1fh[idx] = h; w1fl[idx] = lo;
        }
    } else {
        const int k = bid - 256;
        const int kt = k >> 5, kg = (k >> 3) & 3, e = k & 7;
        const int col = threadIdx.x;
        const float v = w2[(size_t)k * 256 + col];
        const u16 h = bf16_rne(v);
        const u16 lo = bf16_rne(v - bf16_to_f(h));
        const size_t idx = ((size_t)((kt * 4 + kg) * 256) + col) * 8 + e;
        w2fh[idx] = h; w2fl[idx] = lo;
    }
}

// ---------------------------------------------------------------- K3: hf MLP + cosine head, MFMA split-bf16
// Block: 64 tokens (grid = 48 bb * 16 tiles = 768). 4 waves = 4 hid-column quarters.
// LDS swizzle: ushort-index ^= ((row&7)<<3)  (16B-slot spread; applied on write AND read)
#define SWZ(t) (((t) & 7) << 3)

__global__ __launch_bounds__(256, 2)
void k_mlp_high(const float* __restrict__ z,
                const u16* __restrict__ w1fh, const u16* __restrict__ w1fl,
                const u16* __restrict__ w2fh, const u16* __restrict__ w2fl,
                const float* __restrict__ b1,
                const float* __restrict__ lnw, const float* __restrict__ lnb,
                const float* __restrict__ b2,
                const float* __restrict__ prompt,
                float* __restrict__ alpha)
{
    __shared__ u16 SM[64 * 512];          // 64KB: Zhi[64][256] | Zlo[64][256] -> reused as Hhi/Hlo K2-half
    __shared__ float partA[4][64], partB[4][64];
    __shared__ float partP[4];
    __shared__ float mu_s[64], rs_s[64];

    const int tid = threadIdx.x;
    const int l   = tid & 63;
    const int w   = tid >> 6;
    const int lr  = l & 15;
    const int kg  = l >> 4;
    const int tile = blockIdx.x & 15;
    const int bb   = blockIdx.x >> 4;
    const int t0   = tile * 64;

    // ---- stage Z: global f32 [c][t] -> LDS bf16 hi/lo [t][c] (swizzled)
    {
        const int c = tid;
        const float* src = z + ((size_t)bb * 256 + c) * 1024 + t0;
#pragma unroll
        for (int j = 0; j < 64; j += 4) {
            const float4 v = *(const float4*)(src + j);
            const float vv[4] = {v.x, v.y, v.z, v.w};
#pragma unroll
            for (int q = 0; q < 4; ++q) {
                const int t = j + q;
                const u16 h  = bf16_rne(vv[q]);
                const u16 lo = bf16_rne(vv[q] - bf16_to_f(h));
                const int idx = (t * 256 + c) ^ SWZ(t);
                SM[idx] = h;
                SM[16384 + idx] = lo;
            }
        }
    }
    __syncthreads();

    // ---- layer 1: D[64 tok x 512 hid] = Z[64x256] @ W1, split-bf16 (hh + hl + lh)
    const int cb1 = w * 128 + lr;
    f32x4 acc[4][8];
#pragma unroll
    for (int m = 0; m < 4; ++m)
#pragma unroll
        for (int n = 0; n < 8; ++n) acc[m][n] = (f32x4){0.f, 0.f, 0.f, 0.f};

    for (int kt = 0; kt < 8; ++kt) {
        bf16x8 ah[4], al[4];
#pragma unroll
        for (int m = 0; m < 4; ++m) {
            const int idx = ((m * 16 + lr) * 256 + kt * 32 + kg * 8) ^ SWZ(lr);
            ah[m] = *(const bf16x8*)&SM[idx];
            al[m] = *(const bf16x8*)&SM[16384 + idx];
        }
#pragma unroll 2
        for (int n = 0; n < 8; ++n) {
            const size_t wi = ((size_t)((kt * 4 + kg) * 512) + cb1 + n * 16) * 8;
            const bf16x8 bh = *(const bf16x8*)(w1fh + wi);
            const bf16x8 bl = *(const bf16x8*)(w1fl + wi);
#pragma unroll
            for (int m = 0; m < 4; ++m) acc[m][n] = __builtin_amdgcn_mfma_f32_16x16x32_bf16(ah[m], bh, acc[m][n], 0, 0, 0);
#pragma unroll
            for (int m = 0; m < 4; ++m) acc[m][n] = __builtin_amdgcn_mfma_f32_16x16x32_bf16(ah[m], bl, acc[m][n], 0, 0, 0);
#pragma unroll
            for (int m = 0; m < 4; ++m) acc[m][n] = __builtin_amdgcn_mfma_f32_16x16x32_bf16(al[m], bh, acc[m][n], 0, 0, 0);
        }
    }

    // ---- + b1, LN stats (cross-wave)
    float b1v[8];
#pragma unroll
    for (int n = 0; n < 8; ++n) b1v[n] = b1[cb1 + n * 16];
#pragma unroll
    for (int m = 0; m < 4; ++m)
#pragma unroll
        for (int n = 0; n < 8; ++n)
#pragma unroll
            for (int i = 0; i < 4; ++i) acc[m][n][i] += b1v[n];

#pragma unroll
    for (int m = 0; m < 4; ++m) {
        f32x4 s = (f32x4){0.f,0.f,0.f,0.f}, ss = (f32x4){0.f,0.f,0.f,0.f};
#pragma unroll
        for (int n = 0; n < 8; ++n)
#pragma unroll
            for (int i = 0; i < 4; ++i) { s[i] += acc[m][n][i]; ss[i] = fmaf(acc[m][n][i], acc[m][n][i], ss[i]); }
#pragma unroll
        for (int msk = 1; msk < 16; msk <<= 1) {
#pragma unroll
            for (int i = 0; i < 4; ++i) { s[i] += __shfl_xor(s[i], msk); ss[i] += __shfl_xor(ss[i], msk); }
        }
        if (lr == 0) {
#pragma unroll
            for (int i = 0; i < 4; ++i) {
                partA[w][m * 16 + kg * 4 + i] = s[i];
                partB[w][m * 16 + kg * 4 + i] = ss[i];
            }
        }
    }
    __syncthreads();
    if (tid < 64) {
        const float s  = partA[0][tid] + partA[1][tid] + partA[2][tid] + partA[3][tid];
        const float ss = partB[0][tid] + partB[1][tid] + partB[2][tid] + partB[3][tid];
        const float mu  = s * (1.f / 512.f);
        const float var = ss * (1.f / 512.f) - mu * mu;
        mu_s[tid] = mu;
        rs_s[tid] = rsqrtf(var + 1e-5f);
    }
    __syncthreads();

    float lwv[8], lbv[8];
#pragma unroll
    for (int n = 0; n < 8; ++n) { lwv[n] = lnw[cb1 + n * 16]; lbv[n] = lnb[cb1 + n * 16]; }

    // ---- layer 2 in two K2-half phases: H-half (hi+lo) staged in SM, split-bf16 MFMA
    const int cb2 = w * 64 + lr;
    f32x4 acc2[4][4];
#pragma unroll
    for (int m = 0; m < 4; ++m)
#pragma unroll
        for (int n = 0; n < 4; ++n) acc2[m][n] = (f32x4){0.f, 0.f, 0.f, 0.f};

    for (int h2 = 0; h2 < 2; ++h2) {
        __syncthreads();
        if ((w >> 1) == h2) {   // waves owning this K2-half apply LN and publish H-half
#pragma unroll
            for (int m = 0; m < 4; ++m)
#pragma unroll
                for (int n = 0; n < 8; ++n)
#pragma unroll
                    for (int i = 0; i < 4; ++i) {
                        const int t = m * 16 + kg * 4 + i;
                        const float v = (acc[m][n][i] - mu_s[t]) * rs_s[t] * lwv[n] + lbv[n];
                        const u16 h  = bf16_rne(v);
                        const u16 lo = bf16_rne(v - bf16_to_f(h));
                        const int colh = (w & 1) * 128 + n * 16 + lr;
                        const int idx = (t * 256 + colh) ^ SWZ(t);
                        SM[idx] = h;
                        SM[16384 + idx] = lo;
                    }
        }
        __syncthreads();
        for (int k2t = 0; k2t < 8; ++k2t) {
            bf16x8 ah[4], al[4];
#pragma unroll
            for (int m = 0; m < 4; ++m) {
                const int idx = ((m * 16 + lr) * 256 + k2t * 32 + kg * 8) ^ SWZ(lr);
                ah[m] = *(const bf16x8*)&SM[idx];
                al[m] = *(const bf16x8*)&SM[16384 + idx];
            }
#pragma unroll 2
            for (int n = 0; n < 4; ++n) {
                const size_t wi = ((size_t)(((h2 * 8 + k2t) * 4 + kg) * 256) + cb2 + n * 16) * 8;
                const bf16x8 bh = *(const bf16x8*)(w2fh + wi);
                const bf16x8 bl = *(const bf16x8*)(w2fl + wi);
#pragma unroll
                for (int m = 0; m < 4; ++m) acc2[m][n] = __builtin_amdgcn_mfma_f32_16x16x32_bf16(ah[m], bh, acc2[m][n], 0, 0, 0);
#pragma unroll
                for (int m = 0; m < 4; ++m) acc2[m][n] = __builtin_amdgcn_mfma_f32_16x16x32_bf16(ah[m], bl, acc2[m][n], 0, 0, 0);
#pragma unroll
                for (int m = 0; m < 4; ++m) acc2[m][n] = __builtin_amdgcn_mfma_f32_16x16x32_bf16(al[m], bh, acc2[m][n], 0, 0, 0);
            }
        }
    }

    // ---- cosine head
    float b2v[4], prv[4];
#pragma unroll
    for (int n = 0; n < 4; ++n) { b2v[n] = b2[cb2 + n * 16]; prv[n] = prompt[cb2 + n * 16]; }
    {
        float pp = 0.f;
#pragma unroll
        for (int n = 0; n < 4; ++n) pp = fmaf(prv[n], prv[n], pp);
#pragma unroll
        for (int msk = 1; msk < 16; msk <<= 1) pp += __shfl_xor(pp, msk);
        if (l == 0) partP[w] = pp;
    }
#pragma unroll
    for (int m = 0; m < 4; ++m) {
        f32x4 dt = (f32x4){0.f,0.f,0.f,0.f}, nn = (f32x4){0.f,0.f,0.f,0.f};
#pragma unroll
        for (int n = 0; n < 4; ++n)
#pragma unroll
            for (int i = 0; i < 4; ++i) {
                const float q = acc2[m][n][i] + b2v[n];
                dt[i] = fmaf(q, prv[n], dt[i]);
                nn[i] = fmaf(q, q, nn[i]);
            }
#pragma unroll
        for (int msk = 1; msk < 16; msk <<= 1) {
#pragma unroll
            for (int i = 0; i < 4; ++i) { dt[i] += __shfl_xor(dt[i], msk); nn[i] += __shfl_xor(nn[i], msk); }
        }
        if (lr == 0) {
#pragma unroll
            for (int i = 0; i < 4; ++i) {
                partA[w][m * 16 + kg * 4 + i] = dt[i];
                partB[w][m * 16 + kg * 4 + i] = nn[i];
            }
        }
    }
    __syncthreads();
    if (tid < 64) {
        const float dot = partA[0][tid] + partA[1][tid] + partA[2][tid] + partA[3][tid];
        const float nq2 = partB[0][tid] + partB[1][tid] + partB[2][tid] + partB[3][tid];
        const float ppt = partP[0] + partP[1] + partP[2] + partP[3];
        const float nq  = fmaxf(sqrtf(nq2), 1e-8f);
        const float npr = fmaxf(sqrtf(ppt), 1e-8f);
        alpha[(size_t)bb * 1024 + t0 + tid] = fmaxf(dot / (nq * npr), 0.f);
    }
}

// ---------------------------------------------------------------- K4: fused low path: pool-proj + MLP + sigmoid (unchanged)
__global__ __launch_bounds__(256, 2)
void k_mlp_low(const float* __restrict__ sp,
               const float* __restrict__ lw_, const float* __restrict__ lb_,
               const float* __restrict__ w1, const float* __restrict__ b1,
               const float* __restrict__ lnw, const float* __restrict__ lnb,
               const float* __restrict__ w2, const float* __restrict__ b2,
               float* __restrict__ gate)
{
    __shared__ float zt[256 * 16];
    __shared__ float Hl[512 * 20];
    __shared__ float mu_s[16], rs_s[16];
    const int tid  = threadIdx.x;
    const int tile = blockIdx.x & 15;
    const int b    = blockIdx.x >> 4;
    const int t0   = tile * 16;

#pragma unroll
    for (int hh = 0; hh < 2; ++hh) {
        const int s = tid + hh * 256;
        const float* src = sp + ((size_t)b * 512 + s) * 256 + t0;
        *(float4*)&Hl[s * 20 + 0]  = *(const float4*)(src + 0);
        *(float4*)&Hl[s * 20 + 4]  = *(const float4*)(src + 4);
        *(float4*)&Hl[s * 20 + 8]  = *(const float4*)(src + 8);
        *(float4*)&Hl[s * 20 + 12] = *(const float4*)(src + 12);
    }
    __syncthreads();

    {
        float acc[16];
#pragma unroll
        for (int t = 0; t < 16; ++t) acc[t] = 0.f;
        for (int s = 0; s < 512; ++s) {
            const float w = lw_[(size_t)s * 256 + tid];
            float hv[16];
            *(float4*)&hv[0]  = *(const float4*)&Hl[s * 20 + 0];
            *(float4*)&hv[4]  = *(const float4*)&Hl[s * 20 + 4];
            *(float4*)&hv[8]  = *(const float4*)&Hl[s * 20 + 8];
            *(float4*)&hv[12] = *(const float4*)&Hl[s * 20 + 12];
#pragma unroll
            for (int t = 0; t < 16; ++t) acc[t] = fmaf(hv[t], w, acc[t]);
        }
        const float lbv = lb_[tid];
#pragma unroll
        for (int t4 = 0; t4 < 16; t4 += 4)
            *(float4*)&zt[tid * 16 + t4] =
                make_float4(acc[t4] + lbv, acc[t4 + 1] + lbv, acc[t4 + 2] + lbv, acc[t4 + 3] + lbv);
    }
    __syncthreads();

    const int j0 = tid * 2;
    float acc0[16], acc1[16];
#pragma unroll
    for (int t = 0; t < 16; ++t) { acc0[t] = 0.f; acc1[t] = 0.f; }
    for (int k = 0; k < 256; ++k) {
        const float2 w = *(const float2*)(w1 + (size_t)k * 512 + j0);
        float zv[16];
        *(float4*)&zv[0]  = *(const float4*)&zt[k * 16 + 0];
        *(float4*)&zv[4]  = *(const float4*)&zt[k * 16 + 4];
        *(float4*)&zv[8]  = *(const float4*)&zt[k * 16 + 8];
        *(float4*)&zv[12] = *(const float4*)&zt[k * 16 + 12];
#pragma unroll
        for (int t = 0; t < 16; ++t) {
            acc0[t] = fmaf(zv[t], w.x, acc0[t]);
            acc1[t] = fmaf(zv[t], w.y, acc1[t]);
        }
    }
    {
        const float bb0 = b1[j0], bb1 = b1[j0 + 1];
#pragma unroll
        for (int t4 = 0; t4 < 16; t4 += 4) {
            *(float4*)&Hl[j0 * 20 + t4] =
                make_float4(acc0[t4] + bb0, acc0[t4 + 1] + bb0, acc0[t4 + 2] + bb0, acc0[t4 + 3] + bb0);
            *(float4*)&Hl[(j0 + 1) * 20 + t4] =
                make_float4(acc1[t4] + bb1, acc1[t4 + 1] + bb1, acc1[t4 + 2] + bb1, acc1[t4 + 3] + bb1);
        }
    }
    __syncthreads();

    {
        const int t = tid >> 4, g = tid & 15;
        float s = 0.f, ss = 0.f;
        for (int j = g; j < 512; j += 16) {
            const float v = Hl[j * 20 + t];
            s += v; ss = fmaf(v, v, ss);
        }
#pragma unroll
        for (int m = 1; m < 16; m <<= 1) { s += __shfl_xor(s, m); ss += __shfl_xor(ss, m); }
        if (g == 0) {
            const float mu  = s * (1.f / 512.f);
            const float var = ss * (1.f / 512.f) - mu * mu;
            mu_s[t] = mu;
            rs_s[t] = rsqrtf(var + 1e-5f);
        }
    }
    __syncthreads();
    {
        const float lw0 = lnw[j0], lb0 = lnb[j0], lw1 = lnw[j0 + 1], lb1 = lnb[j0 + 1];
#pragma unroll
        for (int t = 0; t < 16; ++t) {
            const float m = mu_s[t], r = rs_s[t];
            Hl[j0 * 20 + t]       = (Hl[j0 * 20 + t] - m) * r * lw0 + lb0;
            Hl[(j0 + 1) * 20 + t] = (Hl[(j0 + 1) * 20 + t] - m) * r * lw1 + lb1;
        }
    }
    __syncthreads();

    {
        float acc2[16];
#pragma unroll
        for (int t = 0; t < 16; ++t) acc2[t] = 0.f;
        for (int k = 0; k < 512; ++k) {
            const float w = w2[(size_t)k * 256 + tid];
            float hv[16];
            *(float4*)&hv[0]  = *(const float4*)&Hl[k * 20 + 0];
            *(float4*)&hv[4]  = *(const float4*)&Hl[k * 20 + 4];
            *(float4*)&hv[8]  = *(const float4*)&Hl[k * 20 + 8];
            *(float4*)&hv[12] = *(const float4*)&Hl[k * 20 + 12];
#pragma unroll
            for (int t = 0; t < 16; ++t) acc2[t] = fmaf(hv[t], w, acc2[t]);
        }
        const float b2v = b2[tid];
        float* gbase = gate + ((size_t)b * 256 + tid) * 256 + t0;
#pragma unroll
        for (int t = 0; t < 16; ++t) {
            const float q = acc2[t] + b2v;
            gbase[t] = 1.f / (1.f + expf(-q));
        }
    }
}

// ---------------------------------------------------------------- K5: apply alpha/gate + inverse Haar (unchanged)
__global__ __launch_bounds__(256)
void k_final(const float* __restrict__ xb,
             const float* __restrict__ alpha,
             const float* __restrict__ gate,
             float* __restrict__ out)
{
    const int bc    = blockIdx.x >> 3;
    const int ytile = blockIdx.x & 7;
    const int x2 = threadIdx.x & 31;
    const int y  = ytile * 8 + (threadIdx.x >> 5);
    const int b  = bc >> 8;

    const float* p = xb + (size_t)bc * (128 * 128) + (2 * y) * 128 + 4 * x2;
    const float4 r0 = *(const float4*)(p);
    const float4 r1 = *(const float4*)(p + 128);

    const int th = (y >> 1) * 32 + x2;
    const float ah = alpha[(size_t)0 * 16384 + b * 1024 + th];
    const float av = alpha[(size_t)1 * 16384 + b * 1024 + th];
    const float ad = alpha[(size_t)2 * 16384 + b * 1024 + th];
    const float g  = gate[(size_t)bc * 256 + (y >> 2) * 16 + (x2 >> 1)];

    float4 o_top, o_bot;
    {
        const float p00 = r0.x, p01 = r0.y, p10 = r1.x, p11 = r1.y;
        const float a  = 0.25f * (p00 + p01 + p10 + p11) * g;
        const float hb = 0.25f * (p00 - p01 + p10 - p11) * ah;
        const float vb = 0.25f * (p00 + p01 - p10 - p11) * av;
        const float db = 0.25f * (p00 - p01 - p10 + p11) * ad;
        o_top.x = a + hb + vb + db;  o_top.y = a - hb + vb - db;
        o_bot.x = a + hb - vb - db;  o_bot.y = a - hb - vb + db;
    }
    {
        const float p00 = r0.z, p01 = r0.w, p10 = r1.z, p11 = r1.w;
        const float a  = 0.25f * (p00 + p01 + p10 + p11) * g;
        const float hb = 0.25f * (p00 - p01 + p10 - p11) * ah;
        const float vb = 0.25f * (p00 + p01 - p10 - p11) * av;
        const float db = 0.25f * (p00 - p01 - p10 + p11) * ad;
        o_top.z = a + hb + vb + db;  o_top.w = a - hb + vb - db;
        o_bot.z = a + hb - vb - db;  o_bot.w = a - hb - vb + db;
    }
    float* q = out + (size_t)bc * (128 * 128) + (2 * y) * 128 + 4 * x2;
    *(float4*)(q)       = o_top;
    *(float4*)(q + 128) = o_bot;
}

// ---------------------------------------------------------------- launch
extern "C" void kernel_launch(void* const* d_in, const int* in_sizes, int n_in,
                              void* d_out, int out_size, void* d_ws, size_t ws_size,
                              hipStream_t stream)
{
    (void)in_sizes; (void)n_in; (void)out_size; (void)ws_size;
    const float* x_big     = (const float*)d_in[0];
    const float* x_small   = (const float*)d_in[1];
    const float* hf_w1     = (const float*)d_in[2];
    const float* hf_b1     = (const float*)d_in[3];
    const float* hf_ln_w   = (const float*)d_in[4];
    const float* hf_ln_b   = (const float*)d_in[5];
    const float* hf_w2     = (const float*)d_in[6];
    const float* hf_b2     = (const float*)d_in[7];
    const float* hf_prompt = (const float*)d_in[8];
    const float* low_w     = (const float*)d_in[9];
    const float* low_b     = (const float*)d_in[10];
    const float* lf_w1     = (const float*)d_in[11];
    const float* lf_b1     = (const float*)d_in[12];
    const float* lf_ln_w   = (const float*)d_in[13];
    const float* lf_ln_b   = (const float*)d_in[14];
    const float* lf_w2     = (const float*)d_in[15];
    const float* lf_b2     = (const float*)d_in[16];
    float* out = (float*)d_out;

    float* ws    = (float*)d_ws;
    float* z     = ws;                               // 3*4096*1024   = 12,582,912 f
    float* sp    = z + (size_t)3 * 4096 * 1024;      // 16*512*256    =  2,097,152 f
    float* alpha = sp + (size_t)16 * 512 * 256;      // 3*16*1024     =     49,152 f
    float* gate  = alpha + (size_t)3 * 16 * 1024;    // 16*256*256    =  1,048,576 f
    u16* w1fh = (u16*)(gate + (size_t)16 * 256 * 256);   // 131072 u16 each
    u16* w1fl = w1fh + 131072;
    u16* w2fh = w1fl + 131072;
    u16* w2fl = w2fh + 131072;

    k_prep       <<<768, 256, 0, stream>>>(hf_w1, hf_w2, w1fh, w1fl, w2fh, w2fl);
    k_haar_tokens<<<4096, 256, 0, stream>>>(x_big, z);
    k_pool_small <<<8192, 256, 0, stream>>>(x_small, sp);
    k_mlp_high   <<<768, 256, 0, stream>>>(z, w1fh, w1fl, w2fh, w2fl,
                                           hf_b1, hf_ln_w, hf_ln_b, hf_b2, hf_prompt, alpha);
    k_mlp_low    <<<256, 256, 0, stream>>>(sp, low_w, low_b, lf_w1, lf_b1,
                                           lf_ln_w, lf_ln_b, lf_w2, lf_b2, gate);
    k_final      <<<32768, 256, 0, stream>>>(x_big, alpha, gate, out);
}

// Round 2
// 1149.406 us; speedup vs baseline: 1.1609x; 1.1609x over previous
//
#include <hip/hip_runtime.h>
#include <cstdint>
#include <cmath>

typedef unsigned short u16;
typedef __bf16 bf16x8 __attribute__((ext_vector_type(8)));
typedef float f32x4 __attribute__((ext_vector_type(4)));

__device__ __forceinline__ u16 bf16_rne(float v) {
    union { float f; uint32_t u; } a; a.f = v;
    uint32_t r = a.u + 0x7fffu + ((a.u >> 16) & 1u);
    return (u16)(r >> 16);
}
__device__ __forceinline__ float bf16_to_f(u16 h) {
    union { uint32_t u; float f; } a; a.u = ((uint32_t)h) << 16;
    return a.f;
}

// Shapes: B=16, Cb=256, H=W=128 -> h2=w2=64. hid=512. Cs=512.
// hf tokens: 32x32=1024/batch/band, 3 bands -> 49152 tokens, dim 256.

// ---------------------------------------------------------------- K1: Haar |band| 2x2-mean tokens
// z layout: [band(3)][b*256+c][1024 tokens], token t = py*32+px
__global__ __launch_bounds__(256)
void k_haar_tokens(const float* __restrict__ xb, float* __restrict__ z)
{
    const int bc = blockIdx.x;            // b*256 + c
    const int px  = threadIdx.x & 31;
    const int py0 = threadIdx.x >> 5;     // [0,8)
    const float* base = xb + (size_t)bc * (128 * 128);
#pragma unroll
    for (int s = 0; s < 4; ++s) {
        const int py = py0 + 8 * s;       // [0,32)
        const float* p = base + (4 * py) * 128 + 4 * px;
        const float4 r0 = *(const float4*)(p);
        const float4 r1 = *(const float4*)(p + 128);
        const float4 r2 = *(const float4*)(p + 256);
        const float4 r3 = *(const float4*)(p + 384);
        float zh = 0.f, zv = 0.f, zd = 0.f;
        {
            const float p00 = r0.x, p01 = r0.y, p10 = r1.x, p11 = r1.y;
            zh += fabsf(p00 - p01 + p10 - p11);
            zv += fabsf(p00 + p01 - p10 - p11);
            zd += fabsf(p00 - p01 - p10 + p11);
        }
        {
            const float p00 = r0.z, p01 = r0.w, p10 = r1.z, p11 = r1.w;
            zh += fabsf(p00 - p01 + p10 - p11);
            zv += fabsf(p00 + p01 - p10 - p11);
            zd += fabsf(p00 - p01 - p10 + p11);
        }
        {
            const float p00 = r2.x, p01 = r2.y, p10 = r3.x, p11 = r3.y;
            zh += fabsf(p00 - p01 + p10 - p11);
            zv += fabsf(p00 + p01 - p10 - p11);
            zd += fabsf(p00 - p01 - p10 + p11);
        }
        {
            const float p00 = r2.z, p01 = r2.w, p10 = r3.z, p11 = r3.w;
            zh += fabsf(p00 - p01 + p10 - p11);
            zv += fabsf(p00 + p01 - p10 - p11);
            zd += fabsf(p00 - p01 - p10 + p11);
        }
        const float sc = 0.0625f;
        const int t = py * 32 + px;
        z[(size_t)(0 * 4096 + bc) * 1024 + t] = zh * sc;
        z[(size_t)(1 * 4096 + bc) * 1024 + t] = zv * sc;
        z[(size_t)(2 * 4096 + bc) * 1024 + t] = zd * sc;
    }
}

// ---------------------------------------------------------------- K2: 4x4 mean pool of x_small
__global__ __launch_bounds__(256)
void k_pool_small(const float* __restrict__ xs, float* __restrict__ sp)
{
    const int bs = blockIdx.x;            // b*512 + s
    const int px = threadIdx.x & 15;
    const int py = threadIdx.x >> 4;
    const float* p = xs + (size_t)bs * 4096 + (4 * py) * 64 + 4 * px;
    float s = 0.f;
#pragma unroll
    for (int r = 0; r < 4; ++r) {
        const float4 v = *(const float4*)(p + 64 * r);
        s += v.x + v.y + v.z + v.w;
    }
    sp[(size_t)bs * 256 + threadIdx.x] = s * 0.0625f;
}

// ---------------------------------------------------------------- K_prep: split W1/W2 into bf16 hi/lo MFMA-fragment layout
// W1f: [kt(8)][kg(4)][col(512)][e(8)], element = W1[kt*32+kg*8+e][col]
// W2f: [k2t(16)][kg(4)][col(256)][e(8)], element = W2[k2t*32+kg*8+e][col]
__global__ __launch_bounds__(256)
void k_prep(const float* __restrict__ w1, const float* __restrict__ w2,
            u16* __restrict__ w1fh, u16* __restrict__ w1fl,
            u16* __restrict__ w2fh, u16* __restrict__ w2fl)
{
    const int bid = blockIdx.x;
    if (bid < 256) {
        const int k = bid;
        const int kt = k >> 5, kg = (k >> 3) & 3, e = k & 7;
        for (int col = threadIdx.x; col < 512; col += 256) {
            const float v = w1[(size_t)k * 512 + col];
            const u16 h = bf16_rne(v);
            const u16 lo = bf16_rne(v - bf16_to_f(h));
            const size_t idx = ((size_t)((kt * 4 + kg) * 512) + col) * 8 + e;
            w1fh[idx] = h; w1fl[idx] = lo;
        }
    } else {
        const int k = bid - 256;
        const int kt = k >> 5, kg = (k >> 3) & 3, e = k & 7;
        const int col = threadIdx.x;
        const float v = w2[(size_t)k * 256 + col];
        const u16 h = bf16_rne(v);
        const u16 lo = bf16_rne(v - bf16_to_f(h));
        const size_t idx = ((size_t)((kt * 4 + kg) * 256) + col) * 8 + e;
        w2fh[idx] = h; w2fl[idx] = lo;
    }
}

// ---------------------------------------------------------------- K3: hf MLP + cosine head, MFMA split-bf16
// Block: 32 tokens (grid = 48 bb * 32 tiles = 1536). 4 waves.
// Layer 1: wave owns 128 hid cols, acc[2][8] (64 VGPR).
// Full LN'd H (hi/lo bf16) published to the 64KB LDS buffer (Z is dead) before layer 2.
// LDS swizzle: u16-index ^= ((row&7)<<3), applied on write AND read.
#define SWZ(t) (((t) & 7) << 3)

__global__ __launch_bounds__(256, 2)
void k_mlp_high(const float* __restrict__ z,
                const u16* __restrict__ w1fh, const u16* __restrict__ w1fl,
                const u16* __restrict__ w2fh, const u16* __restrict__ w2fl,
                const float* __restrict__ b1,
                const float* __restrict__ lnw, const float* __restrict__ lnb,
                const float* __restrict__ b2,
                const float* __restrict__ prompt,
                float* __restrict__ alpha)
{
    __shared__ u16 SM[32768];             // 64KB. Phase A: Zhi[32][256]@0, Zlo@8192. Phase B: Hhi[32][512]@0, Hlo@16384.
    __shared__ float partA[4][32], partB[4][32];
    __shared__ float partP[4];
    __shared__ float mu_s[32], rs_s[32];

    const int tid = threadIdx.x;
    const int l   = tid & 63;
    const int w   = tid >> 6;
    const int lr  = l & 15;
    const int kg  = l >> 4;
    const int tile = blockIdx.x & 31;
    const int bb   = blockIdx.x >> 5;
    const int t0   = tile * 32;

    // ---- stage Z: global f32 [c][t] -> LDS bf16 hi/lo [t][c] (swizzled)
    {
        const int c = tid;
        const float* src = z + ((size_t)bb * 256 + c) * 1024 + t0;
#pragma unroll
        for (int j = 0; j < 32; j += 4) {
            const float4 v = *(const float4*)(src + j);
            const float vv[4] = {v.x, v.y, v.z, v.w};
#pragma unroll
            for (int q = 0; q < 4; ++q) {
                const int t = j + q;
                const u16 h  = bf16_rne(vv[q]);
                const u16 lo = bf16_rne(vv[q] - bf16_to_f(h));
                const int idx = (t * 256 + c) ^ SWZ(t);
                SM[idx] = h;
                SM[8192 + idx] = lo;
            }
        }
    }
    __syncthreads();

    // ---- layer 1: D[32 tok x 512 hid] = Z[32x256] @ W1, split-bf16 (hh + hl + lh)
    const int cb1 = w * 128 + lr;
    f32x4 acc[2][8];
#pragma unroll
    for (int m = 0; m < 2; ++m)
#pragma unroll
        for (int n = 0; n < 8; ++n) acc[m][n] = (f32x4){0.f, 0.f, 0.f, 0.f};

    for (int kt = 0; kt < 8; ++kt) {
        bf16x8 ah[2], al[2];
#pragma unroll
        for (int m = 0; m < 2; ++m) {
            const int idx = ((m * 16 + lr) * 256 + kt * 32 + kg * 8) ^ SWZ(lr);
            ah[m] = *(const bf16x8*)&SM[idx];
            al[m] = *(const bf16x8*)&SM[8192 + idx];
        }
#pragma unroll 2
        for (int n = 0; n < 8; ++n) {
            const size_t wi = ((size_t)((kt * 4 + kg) * 512) + cb1 + n * 16) * 8;
            const bf16x8 bh = *(const bf16x8*)(w1fh + wi);
            const bf16x8 bl = *(const bf16x8*)(w1fl + wi);
#pragma unroll
            for (int m = 0; m < 2; ++m) acc[m][n] = __builtin_amdgcn_mfma_f32_16x16x32_bf16(ah[m], bh, acc[m][n], 0, 0, 0);
#pragma unroll
            for (int m = 0; m < 2; ++m) acc[m][n] = __builtin_amdgcn_mfma_f32_16x16x32_bf16(ah[m], bl, acc[m][n], 0, 0, 0);
#pragma unroll
            for (int m = 0; m < 2; ++m) acc[m][n] = __builtin_amdgcn_mfma_f32_16x16x32_bf16(al[m], bh, acc[m][n], 0, 0, 0);
        }
    }

    // ---- + b1, LN stats (cross-wave)
    float b1v[8];
#pragma unroll
    for (int n = 0; n < 8; ++n) b1v[n] = b1[cb1 + n * 16];
#pragma unroll
    for (int m = 0; m < 2; ++m)
#pragma unroll
        for (int n = 0; n < 8; ++n)
#pragma unroll
            for (int i = 0; i < 4; ++i) acc[m][n][i] += b1v[n];

#pragma unroll
    for (int m = 0; m < 2; ++m) {
        f32x4 s = (f32x4){0.f,0.f,0.f,0.f}, ss = (f32x4){0.f,0.f,0.f,0.f};
#pragma unroll
        for (int n = 0; n < 8; ++n)
#pragma unroll
            for (int i = 0; i < 4; ++i) { s[i] += acc[m][n][i]; ss[i] = fmaf(acc[m][n][i], acc[m][n][i], ss[i]); }
#pragma unroll
        for (int msk = 1; msk < 16; msk <<= 1) {
#pragma unroll
            for (int i = 0; i < 4; ++i) { s[i] += __shfl_xor(s[i], msk); ss[i] += __shfl_xor(ss[i], msk); }
        }
        if (lr == 0) {
#pragma unroll
            for (int i = 0; i < 4; ++i) {
                partA[w][m * 16 + kg * 4 + i] = s[i];
                partB[w][m * 16 + kg * 4 + i] = ss[i];
            }
        }
    }
    __syncthreads();     // also guarantees all Z reads are complete
    if (tid < 32) {
        const float s  = partA[0][tid] + partA[1][tid] + partA[2][tid] + partA[3][tid];
        const float ss = partB[0][tid] + partB[1][tid] + partB[2][tid] + partB[3][tid];
        const float mu  = s * (1.f / 32.f / 16.f);           // 1/512
        const float var = ss * (1.f / 512.f) - mu * mu;
        mu_s[tid] = mu;
        rs_s[tid] = rsqrtf(var + 1e-5f);
    }
    __syncthreads();

    // ---- publish LN'd H (hi/lo bf16) into SM (overwrites Z region)
    {
        float lwv[8], lbv[8];
#pragma unroll
        for (int n = 0; n < 8; ++n) { lwv[n] = lnw[cb1 + n * 16]; lbv[n] = lnb[cb1 + n * 16]; }
#pragma unroll
        for (int m = 0; m < 2; ++m)
#pragma unroll
            for (int n = 0; n < 8; ++n)
#pragma unroll
                for (int i = 0; i < 4; ++i) {
                    const int t = m * 16 + kg * 4 + i;
                    const float v = (acc[m][n][i] - mu_s[t]) * rs_s[t] * lwv[n] + lbv[n];
                    const u16 h  = bf16_rne(v);
                    const u16 lo = bf16_rne(v - bf16_to_f(h));
                    const int col = cb1 + n * 16;
                    const int idx = (t * 512 + col) ^ SWZ(t);
                    SM[idx] = h;
                    SM[16384 + idx] = lo;
                }
    }
    __syncthreads();

    // ---- layer 2: q[32 tok x 256] = H[32x512] @ W2, split-bf16
    const int cb2 = w * 64 + lr;
    f32x4 acc2[2][4];
#pragma unroll
    for (int m = 0; m < 2; ++m)
#pragma unroll
        for (int n = 0; n < 4; ++n) acc2[m][n] = (f32x4){0.f, 0.f, 0.f, 0.f};

    for (int k2t = 0; k2t < 16; ++k2t) {
        bf16x8 ah[2], al[2];
#pragma unroll
        for (int m = 0; m < 2; ++m) {
            const int idx = ((m * 16 + lr) * 512 + k2t * 32 + kg * 8) ^ SWZ(lr);
            ah[m] = *(const bf16x8*)&SM[idx];
            al[m] = *(const bf16x8*)&SM[16384 + idx];
        }
#pragma unroll 2
        for (int n = 0; n < 4; ++n) {
            const size_t wi = ((size_t)((k2t * 4 + kg) * 256) + cb2 + n * 16) * 8;
            const bf16x8 bh = *(const bf16x8*)(w2fh + wi);
            const bf16x8 bl = *(const bf16x8*)(w2fl + wi);
#pragma unroll
            for (int m = 0; m < 2; ++m) acc2[m][n] = __builtin_amdgcn_mfma_f32_16x16x32_bf16(ah[m], bh, acc2[m][n], 0, 0, 0);
#pragma unroll
            for (int m = 0; m < 2; ++m) acc2[m][n] = __builtin_amdgcn_mfma_f32_16x16x32_bf16(ah[m], bl, acc2[m][n], 0, 0, 0);
#pragma unroll
            for (int m = 0; m < 2; ++m) acc2[m][n] = __builtin_amdgcn_mfma_f32_16x16x32_bf16(al[m], bh, acc2[m][n], 0, 0, 0);
        }
    }

    // ---- cosine head
    float b2v[4], prv[4];
#pragma unroll
    for (int n = 0; n < 4; ++n) { b2v[n] = b2[cb2 + n * 16]; prv[n] = prompt[cb2 + n * 16]; }
    {
        float pp = 0.f;
#pragma unroll
        for (int n = 0; n < 4; ++n) pp = fmaf(prv[n], prv[n], pp);
#pragma unroll
        for (int msk = 1; msk < 16; msk <<= 1) pp += __shfl_xor(pp, msk);
        if (l == 0) partP[w] = pp;
    }
#pragma unroll
    for (int m = 0; m < 2; ++m) {
        f32x4 dt = (f32x4){0.f,0.f,0.f,0.f}, nn = (f32x4){0.f,0.f,0.f,0.f};
#pragma unroll
        for (int n = 0; n < 4; ++n)
#pragma unroll
            for (int i = 0; i < 4; ++i) {
                const float q = acc2[m][n][i] + b2v[n];
                dt[i] = fmaf(q, prv[n], dt[i]);
                nn[i] = fmaf(q, q, nn[i]);
            }
#pragma unroll
        for (int msk = 1; msk < 16; msk <<= 1) {
#pragma unroll
            for (int i = 0; i < 4; ++i) { dt[i] += __shfl_xor(dt[i], msk); nn[i] += __shfl_xor(nn[i], msk); }
        }
        if (lr == 0) {
#pragma unroll
            for (int i = 0; i < 4; ++i) {
                partA[w][m * 16 + kg * 4 + i] = dt[i];
                partB[w][m * 16 + kg * 4 + i] = nn[i];
            }
        }
    }
    __syncthreads();
    if (tid < 32) {
        const float dot = partA[0][tid] + partA[1][tid] + partA[2][tid] + partA[3][tid];
        const float nq2 = partB[0][tid] + partB[1][tid] + partB[2][tid] + partB[3][tid];
        const float ppt = partP[0] + partP[1] + partP[2] + partP[3];
        const float nq  = fmaxf(sqrtf(nq2), 1e-8f);
        const float npr = fmaxf(sqrtf(ppt), 1e-8f);
        alpha[(size_t)bb * 1024 + t0 + tid] = fmaxf(dot / (nq * npr), 0.f);
    }
}

// ---------------------------------------------------------------- K4: fused low path: pool-proj + MLP + sigmoid (unchanged)
__global__ __launch_bounds__(256, 2)
void k_mlp_low(const float* __restrict__ sp,
               const float* __restrict__ lw_, const float* __restrict__ lb_,
               const float* __restrict__ w1, const float* __restrict__ b1,
               const float* __restrict__ lnw, const float* __restrict__ lnb,
               const float* __restrict__ w2, const float* __restrict__ b2,
               float* __restrict__ gate)
{
    __shared__ float zt[256 * 16];
    __shared__ float Hl[512 * 20];
    __shared__ float mu_s[16], rs_s[16];
    const int tid  = threadIdx.x;
    const int tile = blockIdx.x & 15;
    const int b    = blockIdx.x >> 4;
    const int t0   = tile * 16;

#pragma unroll
    for (int hh = 0; hh < 2; ++hh) {
        const int s = tid + hh * 256;
        const float* src = sp + ((size_t)b * 512 + s) * 256 + t0;
        *(float4*)&Hl[s * 20 + 0]  = *(const float4*)(src + 0);
        *(float4*)&Hl[s * 20 + 4]  = *(const float4*)(src + 4);
        *(float4*)&Hl[s * 20 + 8]  = *(const float4*)(src + 8);
        *(float4*)&Hl[s * 20 + 12] = *(const float4*)(src + 12);
    }
    __syncthreads();

    {
        float acc[16];
#pragma unroll
        for (int t = 0; t < 16; ++t) acc[t] = 0.f;
        for (int s = 0; s < 512; ++s) {
            const float w = lw_[(size_t)s * 256 + tid];
            float hv[16];
            *(float4*)&hv[0]  = *(const float4*)&Hl[s * 20 + 0];
            *(float4*)&hv[4]  = *(const float4*)&Hl[s * 20 + 4];
            *(float4*)&hv[8]  = *(const float4*)&Hl[s * 20 + 8];
            *(float4*)&hv[12] = *(const float4*)&Hl[s * 20 + 12];
#pragma unroll
            for (int t = 0; t < 16; ++t) acc[t] = fmaf(hv[t], w, acc[t]);
        }
        const float lbv = lb_[tid];
#pragma unroll
        for (int t4 = 0; t4 < 16; t4 += 4)
            *(float4*)&zt[tid * 16 + t4] =
                make_float4(acc[t4] + lbv, acc[t4 + 1] + lbv, acc[t4 + 2] + lbv, acc[t4 + 3] + lbv);
    }
    __syncthreads();

    const int j0 = tid * 2;
    float acc0[16], acc1[16];
#pragma unroll
    for (int t = 0; t < 16; ++t) { acc0[t] = 0.f; acc1[t] = 0.f; }
    for (int k = 0; k < 256; ++k) {
        const float2 w = *(const float2*)(w1 + (size_t)k * 512 + j0);
        float zv[16];
        *(float4*)&zv[0]  = *(const float4*)&zt[k * 16 + 0];
        *(float4*)&zv[4]  = *(const float4*)&zt[k * 16 + 4];
        *(float4*)&zv[8]  = *(const float4*)&zt[k * 16 + 8];
        *(float4*)&zv[12] = *(const float4*)&zt[k * 16 + 12];
#pragma unroll
        for (int t = 0; t < 16; ++t) {
            acc0[t] = fmaf(zv[t], w.x, acc0[t]);
            acc1[t] = fmaf(zv[t], w.y, acc1[t]);
        }
    }
    {
        const float bb0 = b1[j0], bb1 = b1[j0 + 1];
#pragma unroll
        for (int t4 = 0; t4 < 16; t4 += 4) {
            *(float4*)&Hl[j0 * 20 + t4] =
                make_float4(acc0[t4] + bb0, acc0[t4 + 1] + bb0, acc0[t4 + 2] + bb0, acc0[t4 + 3] + bb0);
            *(float4*)&Hl[(j0 + 1) * 20 + t4] =
                make_float4(acc1[t4] + bb1, acc1[t4 + 1] + bb1, acc1[t4 + 2] + bb1, acc1[t4 + 3] + bb1);
        }
    }
    __syncthreads();

    {
        const int t = tid >> 4, g = tid & 15;
        float s = 0.f, ss = 0.f;
        for (int j = g; j < 512; j += 16) {
            const float v = Hl[j * 20 + t];
            s += v; ss = fmaf(v, v, ss);
        }
#pragma unroll
        for (int m = 1; m < 16; m <<= 1) { s += __shfl_xor(s, m); ss += __shfl_xor(ss, m); }
        if (g == 0) {
            const float mu  = s * (1.f / 512.f);
            const float var = ss * (1.f / 512.f) - mu * mu;
            mu_s[t] = mu;
            rs_s[t] = rsqrtf(var + 1e-5f);
        }
    }
    __syncthreads();
    {
        const float lw0 = lnw[j0], lb0 = lnb[j0], lw1 = lnw[j0 + 1], lb1 = lnb[j0 + 1];
#pragma unroll
        for (int t = 0; t < 16; ++t) {
            const float m = mu_s[t], r = rs_s[t];
            Hl[j0 * 20 + t]       = (Hl[j0 * 20 + t] - m) * r * lw0 + lb0;
            Hl[(j0 + 1) * 20 + t] = (Hl[(j0 + 1) * 20 + t] - m) * r * lw1 + lb1;
        }
    }
    __syncthreads();

    {
        float acc2[16];
#pragma unroll
        for (int t = 0; t < 16; ++t) acc2[t] = 0.f;
        for (int k = 0; k < 512; ++k) {
            const float w = w2[(size_t)k * 256 + tid];
            float hv[16];
            *(float4*)&hv[0]  = *(const float4*)&Hl[k * 20 + 0];
            *(float4*)&hv[4]  = *(const float4*)&Hl[k * 20 + 4];
            *(float4*)&hv[8]  = *(const float4*)&Hl[k * 20 + 8];
            *(float4*)&hv[12] = *(const float4*)&Hl[k * 20 + 12];
#pragma unroll
            for (int t = 0; t < 16; ++t) acc2[t] = fmaf(hv[t], w, acc2[t]);
        }
        const float b2v = b2[tid];
        float* gbase = gate + ((size_t)b * 256 + tid) * 256 + t0;
#pragma unroll
        for (int t = 0; t < 16; ++t) {
            const float q = acc2[t] + b2v;
            gbase[t] = 1.f / (1.f + expf(-q));
        }
    }
}

// ---------------------------------------------------------------- K5: apply alpha/gate + inverse Haar (unchanged)
__global__ __launch_bounds__(256)
void k_final(const float* __restrict__ xb,
             const float* __restrict__ alpha,
             const float* __restrict__ gate,
             float* __restrict__ out)
{
    const int bc    = blockIdx.x >> 3;
    const int ytile = blockIdx.x & 7;
    const int x2 = threadIdx.x & 31;
    const int y  = ytile * 8 + (threadIdx.x >> 5);
    const int b  = bc >> 8;

    const float* p = xb + (size_t)bc * (128 * 128) + (2 * y) * 128 + 4 * x2;
    const float4 r0 = *(const float4*)(p);
    const float4 r1 = *(const float4*)(p + 128);

    const int th = (y >> 1) * 32 + x2;
    const float ah = alpha[(size_t)0 * 16384 + b * 1024 + th];
    const float av = alpha[(size_t)1 * 16384 + b * 1024 + th];
    const float ad = alpha[(size_t)2 * 16384 + b * 1024 + th];
    const float g  = gate[(size_t)bc * 256 + (y >> 2) * 16 + (x2 >> 1)];

    float4 o_top, o_bot;
    {
        const float p00 = r0.x, p01 = r0.y, p10 = r1.x, p11 = r1.y;
        const float a  = 0.25f * (p00 + p01 + p10 + p11) * g;
        const float hb = 0.25f * (p00 - p01 + p10 - p11) * ah;
        const float vb = 0.25f * (p00 + p01 - p10 - p11) * av;
        const float db = 0.25f * (p00 - p01 - p10 + p11) * ad;
        o_top.x = a + hb + vb + db;  o_top.y = a - hb + vb - db;
        o_bot.x = a + hb - vb - db;  o_bot.y = a - hb - vb + db;
    }
    {
        const float p00 = r0.z, p01 = r0.w, p10 = r1.z, p11 = r1.w;
        const float a  = 0.25f * (p00 + p01 + p10 + p11) * g;
        const float hb = 0.25f * (p00 - p01 + p10 - p11) * ah;
        const float vb = 0.25f * (p00 + p01 - p10 - p11) * av;
        const float db = 0.25f * (p00 - p01 - p10 + p11) * ad;
        o_top.z = a + hb + vb + db;  o_top.w = a - hb + vb - db;
        o_bot.z = a + hb - vb - db;  o_bot.w = a - hb - vb + db;
    }
    float* q = out + (size_t)bc * (128 * 128) + (2 * y) * 128 + 4 * x2;
    *(float4*)(q)       = o_top;
    *(float4*)(q + 128) = o_bot;
}

// ---------------------------------------------------------------- launch
extern "C" void kernel_launch(void* const* d_in, const int* in_sizes, int n_in,
                              void* d_out, int out_size, void* d_ws, size_t ws_size,
                              hipStream_t stream)
{
    (void)in_sizes; (void)n_in; (void)out_size; (void)ws_size;
    const float* x_big     = (const float*)d_in[0];
    const float* x_small   = (const float*)d_in[1];
    const float* hf_w1     = (const float*)d_in[2];
    const float* hf_b1     = (const float*)d_in[3];
    const float* hf_ln_w   = (const float*)d_in[4];
    const float* hf_ln_b   = (const float*)d_in[5];
    const float* hf_w2     = (const float*)d_in[6];
    const float* hf_b2     = (const float*)d_in[7];
    const float* hf_prompt = (const float*)d_in[8];
    const float* low_w     = (const float*)d_in[9];
    const float* low_b     = (const float*)d_in[10];
    const float* lf_w1     = (const float*)d_in[11];
    const float* lf_b1     = (const float*)d_in[12];
    const float* lf_ln_w   = (const float*)d_in[13];
    const float* lf_ln_b   = (const float*)d_in[14];
    const float* lf_w2     = (const float*)d_in[15];
    const float* lf_b2     = (const float*)d_in[16];
    float* out = (float*)d_out;

    float* ws    = (float*)d_ws;
    float* z     = ws;                               // 3*4096*1024   = 12,582,912 f
    float* sp    = z + (size_t)3 * 4096 * 1024;      // 16*512*256    =  2,097,152 f
    float* alpha = sp + (size_t)16 * 512 * 256;      // 3*16*1024     =     49,152 f
    float* gate  = alpha + (size_t)3 * 16 * 1024;    // 16*256*256    =  1,048,576 f
    u16* w1fh = (u16*)(gate + (size_t)16 * 256 * 256);   // 131072 u16 each
    u16* w1fl = w1fh + 131072;
    u16* w2fh = w1fl + 131072;
    u16* w2fl = w2fh + 131072;

    k_prep       <<<768, 256, 0, stream>>>(hf_w1, hf_w2, w1fh, w1fl, w2fh, w2fl);
    k_haar_tokens<<<4096, 256, 0, stream>>>(x_big, z);
    k_pool_small <<<8192, 256, 0, stream>>>(x_small, sp);
    k_mlp_high   <<<1536, 256, 0, stream>>>(z, w1fh, w1fl, w2fh, w2fl,
                                            hf_b1, hf_ln_w, hf_ln_b, hf_b2, hf_prompt, alpha);
    k_mlp_low    <<<256, 256, 0, stream>>>(sp, low_w, low_b, lf_w1, lf_b1,
                                           lf_ln_w, lf_ln_b, lf_w2, lf_b2, gate);
    k_final      <<<32768, 256, 0, stream>>>(x_big, alpha, gate, out);
}

// Round 3
// 897.074 us; speedup vs baseline: 1.4874x; 1.2813x over previous
//
#include <hip/hip_runtime.h>
#include <cstdint>
#include <cmath>

typedef unsigned short u16;
typedef __bf16 bf16x8 __attribute__((ext_vector_type(8)));
typedef float f32x4 __attribute__((ext_vector_type(4)));

__device__ __forceinline__ u16 bf16_rne(float v) {
    union { float f; uint32_t u; } a; a.f = v;
    uint32_t r = a.u + 0x7fffu + ((a.u >> 16) & 1u);
    return (u16)(r >> 16);
}
__device__ __forceinline__ float bf16_to_f(u16 h) {
    union { uint32_t u; float f; } a; a.u = ((uint32_t)h) << 16;
    return a.f;
}

// Shapes: B=16, Cb=256, H=W=128 -> h2=w2=64. hid=512. Cs=512.
// hf tokens: 32x32=1024/batch/band, 3 bands -> 49152 tokens, dim 256.

// ---------------------------------------------------------------- K1: Haar |band| 2x2-mean tokens
// z layout: [band(3)][b*256+c][1024 tokens], token t = py*32+px
__global__ __launch_bounds__(256)
void k_haar_tokens(const float* __restrict__ xb, float* __restrict__ z)
{
    const int bc = blockIdx.x;            // b*256 + c
    const int px  = threadIdx.x & 31;
    const int py0 = threadIdx.x >> 5;     // [0,8)
    const float* base = xb + (size_t)bc * (128 * 128);
#pragma unroll
    for (int s = 0; s < 4; ++s) {
        const int py = py0 + 8 * s;       // [0,32)
        const float* p = base + (4 * py) * 128 + 4 * px;
        const float4 r0 = *(const float4*)(p);
        const float4 r1 = *(const float4*)(p + 128);
        const float4 r2 = *(const float4*)(p + 256);
        const float4 r3 = *(const float4*)(p + 384);
        float zh = 0.f, zv = 0.f, zd = 0.f;
        {
            const float p00 = r0.x, p01 = r0.y, p10 = r1.x, p11 = r1.y;
            zh += fabsf(p00 - p01 + p10 - p11);
            zv += fabsf(p00 + p01 - p10 - p11);
            zd += fabsf(p00 - p01 - p10 + p11);
        }
        {
            const float p00 = r0.z, p01 = r0.w, p10 = r1.z, p11 = r1.w;
            zh += fabsf(p00 - p01 + p10 - p11);
            zv += fabsf(p00 + p01 - p10 - p11);
            zd += fabsf(p00 - p01 - p10 + p11);
        }
        {
            const float p00 = r2.x, p01 = r2.y, p10 = r3.x, p11 = r3.y;
            zh += fabsf(p00 - p01 + p10 - p11);
            zv += fabsf(p00 + p01 - p10 - p11);
            zd += fabsf(p00 - p01 - p10 + p11);
        }
        {
            const float p00 = r2.z, p01 = r2.w, p10 = r3.z, p11 = r3.w;
            zh += fabsf(p00 - p01 + p10 - p11);
            zv += fabsf(p00 + p01 - p10 - p11);
            zd += fabsf(p00 - p01 - p10 + p11);
        }
        const float sc = 0.0625f;
        const int t = py * 32 + px;
        z[(size_t)(0 * 4096 + bc) * 1024 + t] = zh * sc;
        z[(size_t)(1 * 4096 + bc) * 1024 + t] = zv * sc;
        z[(size_t)(2 * 4096 + bc) * 1024 + t] = zd * sc;
    }
}

// ---------------------------------------------------------------- K2: 4x4 mean pool of x_small
__global__ __launch_bounds__(256)
void k_pool_small(const float* __restrict__ xs, float* __restrict__ sp)
{
    const int bs = blockIdx.x;            // b*512 + s
    const int px = threadIdx.x & 15;
    const int py = threadIdx.x >> 4;
    const float* p = xs + (size_t)bs * 4096 + (4 * py) * 64 + 4 * px;
    float s = 0.f;
#pragma unroll
    for (int r = 0; r < 4; ++r) {
        const float4 v = *(const float4*)(p + 64 * r);
        s += v.x + v.y + v.z + v.w;
    }
    sp[(size_t)bs * 256 + threadIdx.x] = s * 0.0625f;
}

// ---------------------------------------------------------------- K_prep: split W1/W2 into bf16 hi/lo MFMA-fragment layout
// W1f: [kt(8)][kg(4)][col(512)][e(8)], element = W1[kt*32+kg*8+e][col]
// W2f: [k2t(16)][kg(4)][col(256)][e(8)], element = W2[k2t*32+kg*8+e][col]
__global__ __launch_bounds__(256)
void k_prep(const float* __restrict__ w1, const float* __restrict__ w2,
            u16* __restrict__ w1fh, u16* __restrict__ w1fl,
            u16* __restrict__ w2fh, u16* __restrict__ w2fl)
{
    const int bid = blockIdx.x;
    if (bid < 256) {
        const int k = bid;
        const int kt = k >> 5, kg = (k >> 3) & 3, e = k & 7;
        for (int col = threadIdx.x; col < 512; col += 256) {
            const float v = w1[(size_t)k * 512 + col];
            const u16 h = bf16_rne(v);
            const u16 lo = bf16_rne(v - bf16_to_f(h));
            const size_t idx = ((size_t)((kt * 4 + kg) * 512) + col) * 8 + e;
            w1fh[idx] = h; w1fl[idx] = lo;
        }
    } else {
        const int k = bid - 256;
        const int kt = k >> 5, kg = (k >> 3) & 3, e = k & 7;
        const int col = threadIdx.x;
        const float v = w2[(size_t)k * 256 + col];
        const u16 h = bf16_rne(v);
        const u16 lo = bf16_rne(v - bf16_to_f(h));
        const size_t idx = ((size_t)((kt * 4 + kg) * 256) + col) * 8 + e;
        w2fh[idx] = h; w2fl[idx] = lo;
    }
}

// ---------------------------------------------------------------- K3: hf MLP + cosine head, MFMA split-bf16
// Block: 32 tokens (grid = 48 bb * 32 tiles = 1536). 4 waves.
// Layer 1: wave owns 128 hid cols, acc[2][8] (64 VGPR).
// Full LN'd H (hi/lo bf16) published to the 64KB LDS buffer (Z is dead) before layer 2.
// LDS swizzle: u16-index ^= ((row&7)<<3), applied on write AND read.
// NOTE: all accumulator-indexing loops are FULLY unrolled (rule #20: runtime-indexed
// ext_vector arrays go to scratch -- this was an 866 MB/dispatch scratch leak).
#define SWZ(t) (((t) & 7) << 3)

__global__ __launch_bounds__(256, 2)
void k_mlp_high(const float* __restrict__ z,
                const u16* __restrict__ w1fh, const u16* __restrict__ w1fl,
                const u16* __restrict__ w2fh, const u16* __restrict__ w2fl,
                const float* __restrict__ b1,
                const float* __restrict__ lnw, const float* __restrict__ lnb,
                const float* __restrict__ b2,
                const float* __restrict__ prompt,
                float* __restrict__ alpha)
{
    __shared__ u16 SM[32768];             // 64KB. Phase A: Zhi[32][256]@0, Zlo@8192. Phase B: Hhi[32][512]@0, Hlo@16384.
    __shared__ float partA[4][32], partB[4][32];
    __shared__ float partP[4];
    __shared__ float mu_s[32], rs_s[32];

    const int tid = threadIdx.x;
    const int l   = tid & 63;
    const int w   = tid >> 6;
    const int lr  = l & 15;
    const int kg  = l >> 4;
    const int tile = blockIdx.x & 31;
    const int bb   = blockIdx.x >> 5;
    const int t0   = tile * 32;

    // ---- stage Z: global f32 [c][t] -> LDS bf16 hi/lo [t][c] (swizzled)
    {
        const int c = tid;
        const float* src = z + ((size_t)bb * 256 + c) * 1024 + t0;
#pragma unroll
        for (int j = 0; j < 32; j += 4) {
            const float4 v = *(const float4*)(src + j);
            const float vv[4] = {v.x, v.y, v.z, v.w};
#pragma unroll
            for (int q = 0; q < 4; ++q) {
                const int t = j + q;
                const u16 h  = bf16_rne(vv[q]);
                const u16 lo = bf16_rne(vv[q] - bf16_to_f(h));
                const int idx = (t * 256 + c) ^ SWZ(t);
                SM[idx] = h;
                SM[8192 + idx] = lo;
            }
        }
    }
    __syncthreads();

    // ---- layer 1: D[32 tok x 512 hid] = Z[32x256] @ W1, split-bf16 (hh + hl + lh)
    const int cb1 = w * 128 + lr;
    f32x4 acc[2][8];
#pragma unroll
    for (int m = 0; m < 2; ++m)
#pragma unroll
        for (int n = 0; n < 8; ++n) acc[m][n] = (f32x4){0.f, 0.f, 0.f, 0.f};

    for (int kt = 0; kt < 8; ++kt) {
        bf16x8 ah[2], al[2];
#pragma unroll
        for (int m = 0; m < 2; ++m) {
            const int idx = ((m * 16 + lr) * 256 + kt * 32 + kg * 8) ^ SWZ(lr);
            ah[m] = *(const bf16x8*)&SM[idx];
            al[m] = *(const bf16x8*)&SM[8192 + idx];
        }
#pragma unroll
        for (int n = 0; n < 8; ++n) {
            const size_t wi = ((size_t)((kt * 4 + kg) * 512) + cb1 + n * 16) * 8;
            const bf16x8 bh = *(const bf16x8*)(w1fh + wi);
            const bf16x8 bl = *(const bf16x8*)(w1fl + wi);
#pragma unroll
            for (int m = 0; m < 2; ++m) acc[m][n] = __builtin_amdgcn_mfma_f32_16x16x32_bf16(ah[m], bh, acc[m][n], 0, 0, 0);
#pragma unroll
            for (int m = 0; m < 2; ++m) acc[m][n] = __builtin_amdgcn_mfma_f32_16x16x32_bf16(ah[m], bl, acc[m][n], 0, 0, 0);
#pragma unroll
            for (int m = 0; m < 2; ++m) acc[m][n] = __builtin_amdgcn_mfma_f32_16x16x32_bf16(al[m], bh, acc[m][n], 0, 0, 0);
        }
    }

    // ---- + b1, LN stats (cross-wave)
    float b1v[8];
#pragma unroll
    for (int n = 0; n < 8; ++n) b1v[n] = b1[cb1 + n * 16];
#pragma unroll
    for (int m = 0; m < 2; ++m)
#pragma unroll
        for (int n = 0; n < 8; ++n)
#pragma unroll
            for (int i = 0; i < 4; ++i) acc[m][n][i] += b1v[n];

#pragma unroll
    for (int m = 0; m < 2; ++m) {
        f32x4 s = (f32x4){0.f,0.f,0.f,0.f}, ss = (f32x4){0.f,0.f,0.f,0.f};
#pragma unroll
        for (int n = 0; n < 8; ++n)
#pragma unroll
            for (int i = 0; i < 4; ++i) { s[i] += acc[m][n][i]; ss[i] = fmaf(acc[m][n][i], acc[m][n][i], ss[i]); }
#pragma unroll
        for (int msk = 1; msk < 16; msk <<= 1) {
#pragma unroll
            for (int i = 0; i < 4; ++i) { s[i] += __shfl_xor(s[i], msk); ss[i] += __shfl_xor(ss[i], msk); }
        }
        if (lr == 0) {
#pragma unroll
            for (int i = 0; i < 4; ++i) {
                partA[w][m * 16 + kg * 4 + i] = s[i];
                partB[w][m * 16 + kg * 4 + i] = ss[i];
            }
        }
    }
    __syncthreads();     // also guarantees all Z reads are complete
    if (tid < 32) {
        const float s  = partA[0][tid] + partA[1][tid] + partA[2][tid] + partA[3][tid];
        const float ss = partB[0][tid] + partB[1][tid] + partB[2][tid] + partB[3][tid];
        const float mu  = s * (1.f / 512.f);
        const float var = ss * (1.f / 512.f) - mu * mu;
        mu_s[tid] = mu;
        rs_s[tid] = rsqrtf(var + 1e-5f);
    }
    __syncthreads();

    // ---- publish LN'd H (hi/lo bf16) into SM (overwrites Z region)
    {
        float lwv[8], lbv[8];
#pragma unroll
        for (int n = 0; n < 8; ++n) { lwv[n] = lnw[cb1 + n * 16]; lbv[n] = lnb[cb1 + n * 16]; }
#pragma unroll
        for (int m = 0; m < 2; ++m)
#pragma unroll
            for (int n = 0; n < 8; ++n)
#pragma unroll
                for (int i = 0; i < 4; ++i) {
                    const int t = m * 16 + kg * 4 + i;
                    const float v = (acc[m][n][i] - mu_s[t]) * rs_s[t] * lwv[n] + lbv[n];
                    const u16 h  = bf16_rne(v);
                    const u16 lo = bf16_rne(v - bf16_to_f(h));
                    const int col = cb1 + n * 16;
                    const int idx = (t * 512 + col) ^ SWZ(t);
                    SM[idx] = h;
                    SM[16384 + idx] = lo;
                }
    }
    __syncthreads();

    // ---- layer 2: q[32 tok x 256] = H[32x512] @ W2, split-bf16
    const int cb2 = w * 64 + lr;
    f32x4 acc2[2][4];
#pragma unroll
    for (int m = 0; m < 2; ++m)
#pragma unroll
        for (int n = 0; n < 4; ++n) acc2[m][n] = (f32x4){0.f, 0.f, 0.f, 0.f};

    for (int k2t = 0; k2t < 16; ++k2t) {
        bf16x8 ah[2], al[2];
#pragma unroll
        for (int m = 0; m < 2; ++m) {
            const int idx = ((m * 16 + lr) * 512 + k2t * 32 + kg * 8) ^ SWZ(lr);
            ah[m] = *(const bf16x8*)&SM[idx];
            al[m] = *(const bf16x8*)&SM[16384 + idx];
        }
#pragma unroll
        for (int n = 0; n < 4; ++n) {
            const size_t wi = ((size_t)((k2t * 4 + kg) * 256) + cb2 + n * 16) * 8;
            const bf16x8 bh = *(const bf16x8*)(w2fh + wi);
            const bf16x8 bl = *(const bf16x8*)(w2fl + wi);
#pragma unroll
            for (int m = 0; m < 2; ++m) acc2[m][n] = __builtin_amdgcn_mfma_f32_16x16x32_bf16(ah[m], bh, acc2[m][n], 0, 0, 0);
#pragma unroll
            for (int m = 0; m < 2; ++m) acc2[m][n] = __builtin_amdgcn_mfma_f32_16x16x32_bf16(ah[m], bl, acc2[m][n], 0, 0, 0);
#pragma unroll
            for (int m = 0; m < 2; ++m) acc2[m][n] = __builtin_amdgcn_mfma_f32_16x16x32_bf16(al[m], bh, acc2[m][n], 0, 0, 0);
        }
    }

    // ---- cosine head
    float b2v[4], prv[4];
#pragma unroll
    for (int n = 0; n < 4; ++n) { b2v[n] = b2[cb2 + n * 16]; prv[n] = prompt[cb2 + n * 16]; }
    {
        float pp = 0.f;
#pragma unroll
        for (int n = 0; n < 4; ++n) pp = fmaf(prv[n], prv[n], pp);
#pragma unroll
        for (int msk = 1; msk < 16; msk <<= 1) pp += __shfl_xor(pp, msk);
        if (l == 0) partP[w] = pp;
    }
#pragma unroll
    for (int m = 0; m < 2; ++m) {
        f32x4 dt = (f32x4){0.f,0.f,0.f,0.f}, nn = (f32x4){0.f,0.f,0.f,0.f};
#pragma unroll
        for (int n = 0; n < 4; ++n)
#pragma unroll
            for (int i = 0; i < 4; ++i) {
                const float q = acc2[m][n][i] + b2v[n];
                dt[i] = fmaf(q, prv[n], dt[i]);
                nn[i] = fmaf(q, q, nn[i]);
            }
#pragma unroll
        for (int msk = 1; msk < 16; msk <<= 1) {
#pragma unroll
            for (int i = 0; i < 4; ++i) { dt[i] += __shfl_xor(dt[i], msk); nn[i] += __shfl_xor(nn[i], msk); }
        }
        if (lr == 0) {
#pragma unroll
            for (int i = 0; i < 4; ++i) {
                partA[w][m * 16 + kg * 4 + i] = dt[i];
                partB[w][m * 16 + kg * 4 + i] = nn[i];
            }
        }
    }
    __syncthreads();
    if (tid < 32) {
        const float dot = partA[0][tid] + partA[1][tid] + partA[2][tid] + partA[3][tid];
        const float nq2 = partB[0][tid] + partB[1][tid] + partB[2][tid] + partB[3][tid];
        const float ppt = partP[0] + partP[1] + partP[2] + partP[3];
        const float nq  = fmaxf(sqrtf(nq2), 1e-8f);
        const float npr = fmaxf(sqrtf(ppt), 1e-8f);
        alpha[(size_t)bb * 1024 + t0 + tid] = fmaxf(dot / (nq * npr), 0.f);
    }
}

// ---------------------------------------------------------------- K4: fused low path: pool-proj + MLP + sigmoid (unchanged)
__global__ __launch_bounds__(256, 2)
void k_mlp_low(const float* __restrict__ sp,
               const float* __restrict__ lw_, const float* __restrict__ lb_,
               const float* __restrict__ w1, const float* __restrict__ b1,
               const float* __restrict__ lnw, const float* __restrict__ lnb,
               const float* __restrict__ w2, const float* __restrict__ b2,
               float* __restrict__ gate)
{
    __shared__ float zt[256 * 16];
    __shared__ float Hl[512 * 20];
    __shared__ float mu_s[16], rs_s[16];
    const int tid  = threadIdx.x;
    const int tile = blockIdx.x & 15;
    const int b    = blockIdx.x >> 4;
    const int t0   = tile * 16;

#pragma unroll
    for (int hh = 0; hh < 2; ++hh) {
        const int s = tid + hh * 256;
        const float* src = sp + ((size_t)b * 512 + s) * 256 + t0;
        *(float4*)&Hl[s * 20 + 0]  = *(const float4*)(src + 0);
        *(float4*)&Hl[s * 20 + 4]  = *(const float4*)(src + 4);
        *(float4*)&Hl[s * 20 + 8]  = *(const float4*)(src + 8);
        *(float4*)&Hl[s * 20 + 12] = *(const float4*)(src + 12);
    }
    __syncthreads();

    {
        float acc[16];
#pragma unroll
        for (int t = 0; t < 16; ++t) acc[t] = 0.f;
        for (int s = 0; s < 512; ++s) {
            const float w = lw_[(size_t)s * 256 + tid];
            float hv[16];
            *(float4*)&hv[0]  = *(const float4*)&Hl[s * 20 + 0];
            *(float4*)&hv[4]  = *(const float4*)&Hl[s * 20 + 4];
            *(float4*)&hv[8]  = *(const float4*)&Hl[s * 20 + 8];
            *(float4*)&hv[12] = *(const float4*)&Hl[s * 20 + 12];
#pragma unroll
            for (int t = 0; t < 16; ++t) acc[t] = fmaf(hv[t], w, acc[t]);
        }
        const float lbv = lb_[tid];
#pragma unroll
        for (int t4 = 0; t4 < 16; t4 += 4)
            *(float4*)&zt[tid * 16 + t4] =
                make_float4(acc[t4] + lbv, acc[t4 + 1] + lbv, acc[t4 + 2] + lbv, acc[t4 + 3] + lbv);
    }
    __syncthreads();

    const int j0 = tid * 2;
    float acc0[16], acc1[16];
#pragma unroll
    for (int t = 0; t < 16; ++t) { acc0[t] = 0.f; acc1[t] = 0.f; }
    for (int k = 0; k < 256; ++k) {
        const float2 w = *(const float2*)(w1 + (size_t)k * 512 + j0);
        float zv[16];
        *(float4*)&zv[0]  = *(const float4*)&zt[k * 16 + 0];
        *(float4*)&zv[4]  = *(const float4*)&zt[k * 16 + 4];
        *(float4*)&zv[8]  = *(const float4*)&zt[k * 16 + 8];
        *(float4*)&zv[12] = *(const float4*)&zt[k * 16 + 12];
#pragma unroll
        for (int t = 0; t < 16; ++t) {
            acc0[t] = fmaf(zv[t], w.x, acc0[t]);
            acc1[t] = fmaf(zv[t], w.y, acc1[t]);
        }
    }
    {
        const float bb0 = b1[j0], bb1 = b1[j0 + 1];
#pragma unroll
        for (int t4 = 0; t4 < 16; t4 += 4) {
            *(float4*)&Hl[j0 * 20 + t4] =
                make_float4(acc0[t4] + bb0, acc0[t4 + 1] + bb0, acc0[t4 + 2] + bb0, acc0[t4 + 3] + bb0);
            *(float4*)&Hl[(j0 + 1) * 20 + t4] =
                make_float4(acc1[t4] + bb1, acc1[t4 + 1] + bb1, acc1[t4 + 2] + bb1, acc1[t4 + 3] + bb1);
        }
    }
    __syncthreads();

    {
        const int t = tid >> 4, g = tid & 15;
        float s = 0.f, ss = 0.f;
        for (int j = g; j < 512; j += 16) {
            const float v = Hl[j * 20 + t];
            s += v; ss = fmaf(v, v, ss);
        }
#pragma unroll
        for (int m = 1; m < 16; m <<= 1) { s += __shfl_xor(s, m); ss += __shfl_xor(ss, m); }
        if (g == 0) {
            const float mu  = s * (1.f / 512.f);
            const float var = ss * (1.f / 512.f) - mu * mu;
            mu_s[t] = mu;
            rs_s[t] = rsqrtf(var + 1e-5f);
        }
    }
    __syncthreads();
    {
        const float lw0 = lnw[j0], lb0 = lnb[j0], lw1 = lnw[j0 + 1], lb1 = lnb[j0 + 1];
#pragma unroll
        for (int t = 0; t < 16; ++t) {
            const float m = mu_s[t], r = rs_s[t];
            Hl[j0 * 20 + t]       = (Hl[j0 * 20 + t] - m) * r * lw0 + lb0;
            Hl[(j0 + 1) * 20 + t] = (Hl[(j0 + 1) * 20 + t] - m) * r * lw1 + lb1;
        }
    }
    __syncthreads();

    {
        float acc2[16];
#pragma unroll
        for (int t = 0; t < 16; ++t) acc2[t] = 0.f;
        for (int k = 0; k < 512; ++k) {
            const float w = w2[(size_t)k * 256 + tid];
            float hv[16];
            *(float4*)&hv[0]  = *(const float4*)&Hl[k * 20 + 0];
            *(float4*)&hv[4]  = *(const float4*)&Hl[k * 20 + 4];
            *(float4*)&hv[8]  = *(const float4*)&Hl[k * 20 + 8];
            *(float4*)&hv[12] = *(const float4*)&Hl[k * 20 + 12];
#pragma unroll
            for (int t = 0; t < 16; ++t) acc2[t] = fmaf(hv[t], w, acc2[t]);
        }
        const float b2v = b2[tid];
        float* gbase = gate + ((size_t)b * 256 + tid) * 256 + t0;
#pragma unroll
        for (int t = 0; t < 16; ++t) {
            const float q = acc2[t] + b2v;
            gbase[t] = 1.f / (1.f + expf(-q));
        }
    }
}

// ---------------------------------------------------------------- K5: apply alpha/gate + inverse Haar (unchanged)
__global__ __launch_bounds__(256)
void k_final(const float* __restrict__ xb,
             const float* __restrict__ alpha,
             const float* __restrict__ gate,
             float* __restrict__ out)
{
    const int bc    = blockIdx.x >> 3;
    const int ytile = blockIdx.x & 7;
    const int x2 = threadIdx.x & 31;
    const int y  = ytile * 8 + (threadIdx.x >> 5);
    const int b  = bc >> 8;

    const float* p = xb + (size_t)bc * (128 * 128) + (2 * y) * 128 + 4 * x2;
    const float4 r0 = *(const float4*)(p);
    const float4 r1 = *(const float4*)(p + 128);

    const int th = (y >> 1) * 32 + x2;
    const float ah = alpha[(size_t)0 * 16384 + b * 1024 + th];
    const float av = alpha[(size_t)1 * 16384 + b * 1024 + th];
    const float ad = alpha[(size_t)2 * 16384 + b * 1024 + th];
    const float g  = gate[(size_t)bc * 256 + (y >> 2) * 16 + (x2 >> 1)];

    float4 o_top, o_bot;
    {
        const float p00 = r0.x, p01 = r0.y, p10 = r1.x, p11 = r1.y;
        const float a  = 0.25f * (p00 + p01 + p10 + p11) * g;
        const float hb = 0.25f * (p00 - p01 + p10 - p11) * ah;
        const float vb = 0.25f * (p00 + p01 - p10 - p11) * av;
        const float db = 0.25f * (p00 - p01 - p10 + p11) * ad;
        o_top.x = a + hb + vb + db;  o_top.y = a - hb + vb - db;
        o_bot.x = a + hb - vb - db;  o_bot.y = a - hb - vb + db;
    }
    {
        const float p00 = r0.z, p01 = r0.w, p10 = r1.z, p11 = r1.w;
        const float a  = 0.25f * (p00 + p01 + p10 + p11) * g;
        const float hb = 0.25f * (p00 - p01 + p10 - p11) * ah;
        const float vb = 0.25f * (p00 + p01 - p10 - p11) * av;
        const float db = 0.25f * (p00 - p01 - p10 + p11) * ad;
        o_top.z = a + hb + vb + db;  o_top.w = a - hb + vb - db;
        o_bot.z = a + hb - vb - db;  o_bot.w = a - hb - vb + db;
    }
    float* q = out + (size_t)bc * (128 * 128) + (2 * y) * 128 + 4 * x2;
    *(float4*)(q)       = o_top;
    *(float4*)(q + 128) = o_bot;
}

// ---------------------------------------------------------------- launch
extern "C" void kernel_launch(void* const* d_in, const int* in_sizes, int n_in,
                              void* d_out, int out_size, void* d_ws, size_t ws_size,
                              hipStream_t stream)
{
    (void)in_sizes; (void)n_in; (void)out_size; (void)ws_size;
    const float* x_big     = (const float*)d_in[0];
    const float* x_small   = (const float*)d_in[1];
    const float* hf_w1     = (const float*)d_in[2];
    const float* hf_b1     = (const float*)d_in[3];
    const float* hf_ln_w   = (const float*)d_in[4];
    const float* hf_ln_b   = (const float*)d_in[5];
    const float* hf_w2     = (const float*)d_in[6];
    const float* hf_b2     = (const float*)d_in[7];
    const float* hf_prompt = (const float*)d_in[8];
    const float* low_w     = (const float*)d_in[9];
    const float* low_b     = (const float*)d_in[10];
    const float* lf_w1     = (const float*)d_in[11];
    const float* lf_b1     = (const float*)d_in[12];
    const float* lf_ln_w   = (const float*)d_in[13];
    const float* lf_ln_b   = (const float*)d_in[14];
    const float* lf_w2     = (const float*)d_in[15];
    const float* lf_b2     = (const float*)d_in[16];
    float* out = (float*)d_out;

    float* ws    = (float*)d_ws;
    float* z     = ws;                               // 3*4096*1024   = 12,582,912 f
    float* sp    = z + (size_t)3 * 4096 * 1024;      // 16*512*256    =  2,097,152 f
    float* alpha = sp + (size_t)16 * 512 * 256;      // 3*16*1024     =     49,152 f
    float* gate  = alpha + (size_t)3 * 16 * 1024;    // 16*256*256    =  1,048,576 f
    u16* w1fh = (u16*)(gate + (size_t)16 * 256 * 256);   // 131072 u16 each
    u16* w1fl = w1fh + 131072;
    u16* w2fh = w1fl + 131072;
    u16* w2fl = w2fh + 131072;

    k_prep       <<<768, 256, 0, stream>>>(hf_w1, hf_w2, w1fh, w1fl, w2fh, w2fl);
    k_haar_tokens<<<4096, 256, 0, stream>>>(x_big, z);
    k_pool_small <<<8192, 256, 0, stream>>>(x_small, sp);
    k_mlp_high   <<<1536, 256, 0, stream>>>(z, w1fh, w1fl, w2fh, w2fl,
                                            hf_b1, hf_ln_w, hf_ln_b, hf_b2, hf_prompt, alpha);
    k_mlp_low    <<<256, 256, 0, stream>>>(sp, low_w, low_b, lf_w1, lf_b1,
                                           lf_ln_w, lf_ln_b, lf_w2, lf_b2, gate);
    k_final      <<<32768, 256, 0, stream>>>(x_big, alpha, gate, out);
}

// Round 4
// 834.081 us; speedup vs baseline: 1.5998x; 1.0755x over previous
//
#include <hip/hip_runtime.h>
#include <cstdint>
#include <cmath>

typedef unsigned short u16;
typedef __bf16 bf16x8 __attribute__((ext_vector_type(8)));
typedef float f32x4 __attribute__((ext_vector_type(4)));

__device__ __forceinline__ u16 bf16_rne(float v) {
    union { float f; uint32_t u; } a; a.f = v;
    uint32_t r = a.u + 0x7fffu + ((a.u >> 16) & 1u);
    return (u16)(r >> 16);
}
__device__ __forceinline__ float bf16_to_f(u16 h) {
    union { uint32_t u; float f; } a; a.u = ((uint32_t)h) << 16;
    return a.f;
}

// Shapes: B=16, Cb=256, H=W=128 -> h2=w2=64. hid=512. Cs=512.
// hf tokens: 32x32=1024/batch/band, 3 bands -> 49152 tokens, dim 256.
// lf tokens: 16x16=256/batch -> 4096 tokens.

// ---------------------------------------------------------------- K1: Haar |band| 2x2-mean tokens
// z layout: [band(3)][b*256+c][1024 tokens], token t = py*32+px
__global__ __launch_bounds__(256)
void k_haar_tokens(const float* __restrict__ xb, float* __restrict__ z)
{
    const int bc = blockIdx.x;            // b*256 + c
    const int px  = threadIdx.x & 31;
    const int py0 = threadIdx.x >> 5;     // [0,8)
    const float* base = xb + (size_t)bc * (128 * 128);
#pragma unroll
    for (int s = 0; s < 4; ++s) {
        const int py = py0 + 8 * s;       // [0,32)
        const float* p = base + (4 * py) * 128 + 4 * px;
        const float4 r0 = *(const float4*)(p);
        const float4 r1 = *(const float4*)(p + 128);
        const float4 r2 = *(const float4*)(p + 256);
        const float4 r3 = *(const float4*)(p + 384);
        float zh = 0.f, zv = 0.f, zd = 0.f;
        {
            const float p00 = r0.x, p01 = r0.y, p10 = r1.x, p11 = r1.y;
            zh += fabsf(p00 - p01 + p10 - p11);
            zv += fabsf(p00 + p01 - p10 - p11);
            zd += fabsf(p00 - p01 - p10 + p11);
        }
        {
            const float p00 = r0.z, p01 = r0.w, p10 = r1.z, p11 = r1.w;
            zh += fabsf(p00 - p01 + p10 - p11);
            zv += fabsf(p00 + p01 - p10 - p11);
            zd += fabsf(p00 - p01 - p10 + p11);
        }
        {
            const float p00 = r2.x, p01 = r2.y, p10 = r3.x, p11 = r3.y;
            zh += fabsf(p00 - p01 + p10 - p11);
            zv += fabsf(p00 + p01 - p10 - p11);
            zd += fabsf(p00 - p01 - p10 + p11);
        }
        {
            const float p00 = r2.z, p01 = r2.w, p10 = r3.z, p11 = r3.w;
            zh += fabsf(p00 - p01 + p10 - p11);
            zv += fabsf(p00 + p01 - p10 - p11);
            zd += fabsf(p00 - p01 - p10 + p11);
        }
        const float sc = 0.0625f;
        const int t = py * 32 + px;
        z[(size_t)(0 * 4096 + bc) * 1024 + t] = zh * sc;
        z[(size_t)(1 * 4096 + bc) * 1024 + t] = zv * sc;
        z[(size_t)(2 * 4096 + bc) * 1024 + t] = zd * sc;
    }
}

// ---------------------------------------------------------------- K2: 4x4 mean pool of x_small
__global__ __launch_bounds__(256)
void k_pool_small(const float* __restrict__ xs, float* __restrict__ sp)
{
    const int bs = blockIdx.x;            // b*512 + s
    const int px = threadIdx.x & 15;
    const int py = threadIdx.x >> 4;
    const float* p = xs + (size_t)bs * 4096 + (4 * py) * 64 + 4 * px;
    float s = 0.f;
#pragma unroll
    for (int r = 0; r < 4; ++r) {
        const float4 v = *(const float4*)(p + 64 * r);
        s += v.x + v.y + v.z + v.w;
    }
    sp[(size_t)bs * 256 + threadIdx.x] = s * 0.0625f;
}

// ---------------------------------------------------------------- K_prep: split weights into bf16 hi/lo MFMA-fragment layout
// frag layout (ncol = output cols): [kt][kg(4)][col(ncol)][e(8)], element = W[kt*32+kg*8+e][col]
__device__ __forceinline__ void split_row(const float* __restrict__ src,
                                          u16* __restrict__ dh, u16* __restrict__ dl,
                                          int k, int ncol, int tidx)
{
    const int kt = k >> 5, kg = (k >> 3) & 3, e = k & 7;
    for (int col = tidx; col < ncol; col += 256) {
        const float v = src[(size_t)k * ncol + col];
        const u16 h  = bf16_rne(v);
        const u16 lo = bf16_rne(v - bf16_to_f(h));
        const size_t idx = ((size_t)((kt * 4 + kg) * ncol) + col) * 8 + e;
        dh[idx] = h; dl[idx] = lo;
    }
}

__global__ __launch_bounds__(256)
void k_prep(const float* __restrict__ w1,  const float* __restrict__ w2,
            const float* __restrict__ low, const float* __restrict__ v1,
            const float* __restrict__ v2,
            u16* __restrict__ w1fh,  u16* __restrict__ w1fl,
            u16* __restrict__ w2fh,  u16* __restrict__ w2fl,
            u16* __restrict__ lowfh, u16* __restrict__ lowfl,
            u16* __restrict__ v1fh,  u16* __restrict__ v1fl,
            u16* __restrict__ v2fh,  u16* __restrict__ v2fl)
{
    const int bid = blockIdx.x;
    if      (bid < 256)  split_row(w1,  w1fh,  w1fl,  bid,        512, threadIdx.x);
    else if (bid < 768)  split_row(w2,  w2fh,  w2fl,  bid - 256,  256, threadIdx.x);
    else if (bid < 1280) split_row(low, lowfh, lowfl, bid - 768,  256, threadIdx.x);
    else if (bid < 1536) split_row(v1,  v1fh,  v1fl,  bid - 1280, 512, threadIdx.x);
    else                 split_row(v2,  v2fh,  v2fl,  bid - 1536, 256, threadIdx.x);
}

// LDS swizzle: u16-index ^= ((row&7)<<3), applied on write AND read (involution).
#define SWZ(t) (((t) & 7) << 3)

// ---------------------------------------------------------------- K3: hf MLP + cosine head, MFMA split-bf16
// Block: 32 tokens (grid = 48 bb * 32 tiles = 1536). 4 waves.
// All accumulator-indexing loops FULLY unrolled (rule #20: runtime-indexed ext_vector -> scratch).
__global__ __launch_bounds__(256, 2)
void k_mlp_high(const float* __restrict__ z,
                const u16* __restrict__ w1fh, const u16* __restrict__ w1fl,
                const u16* __restrict__ w2fh, const u16* __restrict__ w2fl,
                const float* __restrict__ b1,
                const float* __restrict__ lnw, const float* __restrict__ lnb,
                const float* __restrict__ b2,
                const float* __restrict__ prompt,
                float* __restrict__ alpha)
{
    __shared__ u16 SM[32768];             // 64KB. Phase A: Zhi[32][256]@0, Zlo@8192. Phase B: Hhi[32][512]@0, Hlo@16384.
    __shared__ float partA[4][32], partB[4][32];
    __shared__ float partP[4];
    __shared__ float mu_s[32], rs_s[32];

    const int tid = threadIdx.x;
    const int l   = tid & 63;
    const int w   = tid >> 6;
    const int lr  = l & 15;
    const int kg  = l >> 4;
    const int tile = blockIdx.x & 31;
    const int bb   = blockIdx.x >> 5;
    const int t0   = tile * 32;

    // ---- stage Z: global f32 [c][t] -> LDS bf16 hi/lo [t][c] (swizzled)
    {
        const int c = tid;
        const float* src = z + ((size_t)bb * 256 + c) * 1024 + t0;
#pragma unroll
        for (int j = 0; j < 32; j += 4) {
            const float4 v = *(const float4*)(src + j);
            const float vv[4] = {v.x, v.y, v.z, v.w};
#pragma unroll
            for (int q = 0; q < 4; ++q) {
                const int t = j + q;
                const u16 h  = bf16_rne(vv[q]);
                const u16 lo = bf16_rne(vv[q] - bf16_to_f(h));
                const int idx = (t * 256 + c) ^ SWZ(t);
                SM[idx] = h;
                SM[8192 + idx] = lo;
            }
        }
    }
    __syncthreads();

    // ---- layer 1: D[32 tok x 512 hid] = Z[32x256] @ W1, split-bf16 (hh + hl + lh)
    const int cb1 = w * 128 + lr;
    f32x4 acc[2][8];
#pragma unroll
    for (int m = 0; m < 2; ++m)
#pragma unroll
        for (int n = 0; n < 8; ++n) acc[m][n] = (f32x4){0.f, 0.f, 0.f, 0.f};

    for (int kt = 0; kt < 8; ++kt) {
        bf16x8 ah[2], al[2];
#pragma unroll
        for (int m = 0; m < 2; ++m) {
            const int idx = ((m * 16 + lr) * 256 + kt * 32 + kg * 8) ^ SWZ(lr);
            ah[m] = *(const bf16x8*)&SM[idx];
            al[m] = *(const bf16x8*)&SM[8192 + idx];
        }
#pragma unroll
        for (int n = 0; n < 8; ++n) {
            const size_t wi = ((size_t)((kt * 4 + kg) * 512) + cb1 + n * 16) * 8;
            const bf16x8 bh = *(const bf16x8*)(w1fh + wi);
            const bf16x8 bl = *(const bf16x8*)(w1fl + wi);
#pragma unroll
            for (int m = 0; m < 2; ++m) acc[m][n] = __builtin_amdgcn_mfma_f32_16x16x32_bf16(ah[m], bh, acc[m][n], 0, 0, 0);
#pragma unroll
            for (int m = 0; m < 2; ++m) acc[m][n] = __builtin_amdgcn_mfma_f32_16x16x32_bf16(ah[m], bl, acc[m][n], 0, 0, 0);
#pragma unroll
            for (int m = 0; m < 2; ++m) acc[m][n] = __builtin_amdgcn_mfma_f32_16x16x32_bf16(al[m], bh, acc[m][n], 0, 0, 0);
        }
    }

    // ---- + b1, LN stats (cross-wave)
    float b1v[8];
#pragma unroll
    for (int n = 0; n < 8; ++n) b1v[n] = b1[cb1 + n * 16];
#pragma unroll
    for (int m = 0; m < 2; ++m)
#pragma unroll
        for (int n = 0; n < 8; ++n)
#pragma unroll
            for (int i = 0; i < 4; ++i) acc[m][n][i] += b1v[n];

#pragma unroll
    for (int m = 0; m < 2; ++m) {
        f32x4 s = (f32x4){0.f,0.f,0.f,0.f}, ss = (f32x4){0.f,0.f,0.f,0.f};
#pragma unroll
        for (int n = 0; n < 8; ++n)
#pragma unroll
            for (int i = 0; i < 4; ++i) { s[i] += acc[m][n][i]; ss[i] = fmaf(acc[m][n][i], acc[m][n][i], ss[i]); }
#pragma unroll
        for (int msk = 1; msk < 16; msk <<= 1) {
#pragma unroll
            for (int i = 0; i < 4; ++i) { s[i] += __shfl_xor(s[i], msk); ss[i] += __shfl_xor(ss[i], msk); }
        }
        if (lr == 0) {
#pragma unroll
            for (int i = 0; i < 4; ++i) {
                partA[w][m * 16 + kg * 4 + i] = s[i];
                partB[w][m * 16 + kg * 4 + i] = ss[i];
            }
        }
    }
    __syncthreads();
    if (tid < 32) {
        const float s  = partA[0][tid] + partA[1][tid] + partA[2][tid] + partA[3][tid];
        const float ss = partB[0][tid] + partB[1][tid] + partB[2][tid] + partB[3][tid];
        const float mu  = s * (1.f / 512.f);
        const float var = ss * (1.f / 512.f) - mu * mu;
        mu_s[tid] = mu;
        rs_s[tid] = rsqrtf(var + 1e-5f);
    }
    __syncthreads();

    // ---- publish LN'd H (hi/lo bf16) into SM (overwrites Z region)
    {
        float lwv[8], lbv[8];
#pragma unroll
        for (int n = 0; n < 8; ++n) { lwv[n] = lnw[cb1 + n * 16]; lbv[n] = lnb[cb1 + n * 16]; }
#pragma unroll
        for (int m = 0; m < 2; ++m)
#pragma unroll
            for (int n = 0; n < 8; ++n)
#pragma unroll
                for (int i = 0; i < 4; ++i) {
                    const int t = m * 16 + kg * 4 + i;
                    const float v = (acc[m][n][i] - mu_s[t]) * rs_s[t] * lwv[n] + lbv[n];
                    const u16 h  = bf16_rne(v);
                    const u16 lo = bf16_rne(v - bf16_to_f(h));
                    const int col = cb1 + n * 16;
                    const int idx = (t * 512 + col) ^ SWZ(t);
                    SM[idx] = h;
                    SM[16384 + idx] = lo;
                }
    }
    __syncthreads();

    // ---- layer 2: q[32 tok x 256] = H[32x512] @ W2, split-bf16
    const int cb2 = w * 64 + lr;
    f32x4 acc2[2][4];
#pragma unroll
    for (int m = 0; m < 2; ++m)
#pragma unroll
        for (int n = 0; n < 4; ++n) acc2[m][n] = (f32x4){0.f, 0.f, 0.f, 0.f};

    for (int k2t = 0; k2t < 16; ++k2t) {
        bf16x8 ah[2], al[2];
#pragma unroll
        for (int m = 0; m < 2; ++m) {
            const int idx = ((m * 16 + lr) * 512 + k2t * 32 + kg * 8) ^ SWZ(lr);
            ah[m] = *(const bf16x8*)&SM[idx];
            al[m] = *(const bf16x8*)&SM[16384 + idx];
        }
#pragma unroll
        for (int n = 0; n < 4; ++n) {
            const size_t wi = ((size_t)((k2t * 4 + kg) * 256) + cb2 + n * 16) * 8;
            const bf16x8 bh = *(const bf16x8*)(w2fh + wi);
            const bf16x8 bl = *(const bf16x8*)(w2fl + wi);
#pragma unroll
            for (int m = 0; m < 2; ++m) acc2[m][n] = __builtin_amdgcn_mfma_f32_16x16x32_bf16(ah[m], bh, acc2[m][n], 0, 0, 0);
#pragma unroll
            for (int m = 0; m < 2; ++m) acc2[m][n] = __builtin_amdgcn_mfma_f32_16x16x32_bf16(ah[m], bl, acc2[m][n], 0, 0, 0);
#pragma unroll
            for (int m = 0; m < 2; ++m) acc2[m][n] = __builtin_amdgcn_mfma_f32_16x16x32_bf16(al[m], bh, acc2[m][n], 0, 0, 0);
        }
    }

    // ---- cosine head
    float b2v[4], prv[4];
#pragma unroll
    for (int n = 0; n < 4; ++n) { b2v[n] = b2[cb2 + n * 16]; prv[n] = prompt[cb2 + n * 16]; }
    {
        float pp = 0.f;
#pragma unroll
        for (int n = 0; n < 4; ++n) pp = fmaf(prv[n], prv[n], pp);
#pragma unroll
        for (int msk = 1; msk < 16; msk <<= 1) pp += __shfl_xor(pp, msk);
        if (l == 0) partP[w] = pp;
    }
#pragma unroll
    for (int m = 0; m < 2; ++m) {
        f32x4 dt = (f32x4){0.f,0.f,0.f,0.f}, nn = (f32x4){0.f,0.f,0.f,0.f};
#pragma unroll
        for (int n = 0; n < 4; ++n)
#pragma unroll
            for (int i = 0; i < 4; ++i) {
                const float q = acc2[m][n][i] + b2v[n];
                dt[i] = fmaf(q, prv[n], dt[i]);
                nn[i] = fmaf(q, q, nn[i]);
            }
#pragma unroll
        for (int msk = 1; msk < 16; msk <<= 1) {
#pragma unroll
            for (int i = 0; i < 4; ++i) { dt[i] += __shfl_xor(dt[i], msk); nn[i] += __shfl_xor(nn[i], msk); }
        }
        if (lr == 0) {
#pragma unroll
            for (int i = 0; i < 4; ++i) {
                partA[w][m * 16 + kg * 4 + i] = dt[i];
                partB[w][m * 16 + kg * 4 + i] = nn[i];
            }
        }
    }
    __syncthreads();
    if (tid < 32) {
        const float dot = partA[0][tid] + partA[1][tid] + partA[2][tid] + partA[3][tid];
        const float nq2 = partB[0][tid] + partB[1][tid] + partB[2][tid] + partB[3][tid];
        const float ppt = partP[0] + partP[1] + partP[2] + partP[3];
        const float nq  = fmaxf(sqrtf(nq2), 1e-8f);
        const float npr = fmaxf(sqrtf(ppt), 1e-8f);
        alpha[(size_t)bb * 1024 + t0 + tid] = fmaxf(dot / (nq * npr), 0.f);
    }
}

// ---------------------------------------------------------------- K4: low path, MFMA split-bf16
// Block: 16 tokens (grid = 16 b * 16 tiles = 256). 4 waves.
// Phase A: k_tok[16x256] = spT[16x512] @ low_w. Then MLP 256->512->256 + sigmoid.
// gate layout: [b*256+d][256 tokens]
__global__ __launch_bounds__(256, 2)
void k_mlp_low(const float* __restrict__ sp,
               const u16* __restrict__ lowfh, const u16* __restrict__ lowfl,
               const float* __restrict__ lb_,
               const u16* __restrict__ w1fh, const u16* __restrict__ w1fl,
               const float* __restrict__ b1,
               const float* __restrict__ lnw, const float* __restrict__ lnb,
               const u16* __restrict__ w2fh, const u16* __restrict__ w2fl,
               const float* __restrict__ b2,
               float* __restrict__ gate)
{
    __shared__ u16 SM[16384];             // 32KB. A: SPhi[16][512]@0, SPlo@8192. B: Khi[16][256]@0, Klo@4096. C: Hhi[16][512]@0, Hlo@8192.
    __shared__ float partA[4][16], partB[4][16];
    __shared__ float mu_s[16], rs_s[16];

    const int tid = threadIdx.x;
    const int l   = tid & 63;
    const int w   = tid >> 6;
    const int lr  = l & 15;
    const int kg  = l >> 4;
    const int tile = blockIdx.x & 15;
    const int b    = blockIdx.x >> 4;
    const int t0   = tile * 16;

    // ---- stage sp tile: global f32 [s][t] -> LDS bf16 hi/lo [t][s] (swizzled)
#pragma unroll
    for (int hh = 0; hh < 2; ++hh) {
        const int s = tid + hh * 256;
        const float* src = sp + ((size_t)b * 512 + s) * 256 + t0;
#pragma unroll
        for (int j = 0; j < 16; j += 4) {
            const float4 v = *(const float4*)(src + j);
            const float vv[4] = {v.x, v.y, v.z, v.w};
#pragma unroll
            for (int q = 0; q < 4; ++q) {
                const int t = j + q;
                const u16 h  = bf16_rne(vv[q]);
                const u16 lo = bf16_rne(vv[q] - bf16_to_f(h));
                const int idx = (t * 512 + s) ^ SWZ(t);
                SM[idx] = h;
                SM[8192 + idx] = lo;
            }
        }
    }
    __syncthreads();

    // ---- phase A: k_tok[16 x 256] = spT[16x512] @ low_w, split-bf16
    const int cbA = w * 64 + lr;
    f32x4 accA[4];
#pragma unroll
    for (int n = 0; n < 4; ++n) accA[n] = (f32x4){0.f, 0.f, 0.f, 0.f};

    for (int kt = 0; kt < 16; ++kt) {
        const int idx = (lr * 512 + kt * 32 + kg * 8) ^ SWZ(lr);
        const bf16x8 ah = *(const bf16x8*)&SM[idx];
        const bf16x8 al = *(const bf16x8*)&SM[8192 + idx];
#pragma unroll
        for (int n = 0; n < 4; ++n) {
            const size_t wi = ((size_t)((kt * 4 + kg) * 256) + cbA + n * 16) * 8;
            const bf16x8 bh = *(const bf16x8*)(lowfh + wi);
            const bf16x8 bl = *(const bf16x8*)(lowfl + wi);
            accA[n] = __builtin_amdgcn_mfma_f32_16x16x32_bf16(ah, bh, accA[n], 0, 0, 0);
            accA[n] = __builtin_amdgcn_mfma_f32_16x16x32_bf16(ah, bl, accA[n], 0, 0, 0);
            accA[n] = __builtin_amdgcn_mfma_f32_16x16x32_bf16(al, bh, accA[n], 0, 0, 0);
        }
    }
    __syncthreads();      // all sp reads done

    // ---- publish k_tok (hi/lo bf16) into SM[0..8191]
    {
        float lbv[4];
#pragma unroll
        for (int n = 0; n < 4; ++n) lbv[n] = lb_[cbA + n * 16];
#pragma unroll
        for (int n = 0; n < 4; ++n)
#pragma unroll
            for (int i = 0; i < 4; ++i) {
                const int t = kg * 4 + i;
                const float v = accA[n][i] + lbv[n];
                const u16 h  = bf16_rne(v);
                const u16 lo = bf16_rne(v - bf16_to_f(h));
                const int idx = (t * 256 + cbA + n * 16) ^ SWZ(t);
                SM[idx] = h;
                SM[4096 + idx] = lo;
            }
    }
    __syncthreads();

    // ---- layer 1: D[16 tok x 512 hid] = K[16x256] @ W1, split-bf16
    const int cb1 = w * 128 + lr;
    f32x4 acc1[8];
#pragma unroll
    for (int n = 0; n < 8; ++n) acc1[n] = (f32x4){0.f, 0.f, 0.f, 0.f};

    for (int kt = 0; kt < 8; ++kt) {
        const int idx = (lr * 256 + kt * 32 + kg * 8) ^ SWZ(lr);
        const bf16x8 ah = *(const bf16x8*)&SM[idx];
        const bf16x8 al = *(const bf16x8*)&SM[4096 + idx];
#pragma unroll
        for (int n = 0; n < 8; ++n) {
            const size_t wi = ((size_t)((kt * 4 + kg) * 512) + cb1 + n * 16) * 8;
            const bf16x8 bh = *(const bf16x8*)(w1fh + wi);
            const bf16x8 bl = *(const bf16x8*)(w1fl + wi);
            acc1[n] = __builtin_amdgcn_mfma_f32_16x16x32_bf16(ah, bh, acc1[n], 0, 0, 0);
            acc1[n] = __builtin_amdgcn_mfma_f32_16x16x32_bf16(ah, bl, acc1[n], 0, 0, 0);
            acc1[n] = __builtin_amdgcn_mfma_f32_16x16x32_bf16(al, bh, acc1[n], 0, 0, 0);
        }
    }

    // ---- + b1, LN stats
    {
        float b1v[8];
#pragma unroll
        for (int n = 0; n < 8; ++n) b1v[n] = b1[cb1 + n * 16];
#pragma unroll
        for (int n = 0; n < 8; ++n)
#pragma unroll
            for (int i = 0; i < 4; ++i) acc1[n][i] += b1v[n];

        f32x4 s = (f32x4){0.f,0.f,0.f,0.f}, ss = (f32x4){0.f,0.f,0.f,0.f};
#pragma unroll
        for (int n = 0; n < 8; ++n)
#pragma unroll
            for (int i = 0; i < 4; ++i) { s[i] += acc1[n][i]; ss[i] = fmaf(acc1[n][i], acc1[n][i], ss[i]); }
#pragma unroll
        for (int msk = 1; msk < 16; msk <<= 1) {
#pragma unroll
            for (int i = 0; i < 4; ++i) { s[i] += __shfl_xor(s[i], msk); ss[i] += __shfl_xor(ss[i], msk); }
        }
        if (lr == 0) {
#pragma unroll
            for (int i = 0; i < 4; ++i) {
                partA[w][kg * 4 + i] = s[i];
                partB[w][kg * 4 + i] = ss[i];
            }
        }
    }
    __syncthreads();
    if (tid < 16) {
        const float s  = partA[0][tid] + partA[1][tid] + partA[2][tid] + partA[3][tid];
        const float ss = partB[0][tid] + partB[1][tid] + partB[2][tid] + partB[3][tid];
        const float mu  = s * (1.f / 512.f);
        const float var = ss * (1.f / 512.f) - mu * mu;
        mu_s[tid] = mu;
        rs_s[tid] = rsqrtf(var + 1e-5f);
    }
    __syncthreads();

    // ---- publish LN'd H (hi/lo bf16) into SM (overwrites k_tok)
    {
        float lwv[8], lbv[8];
#pragma unroll
        for (int n = 0; n < 8; ++n) { lwv[n] = lnw[cb1 + n * 16]; lbv[n] = lnb[cb1 + n * 16]; }
#pragma unroll
        for (int n = 0; n < 8; ++n)
#pragma unroll
            for (int i = 0; i < 4; ++i) {
                const int t = kg * 4 + i;
                const float v = (acc1[n][i] - mu_s[t]) * rs_s[t] * lwv[n] + lbv[n];
                const u16 h  = bf16_rne(v);
                const u16 lo = bf16_rne(v - bf16_to_f(h));
                const int idx = (t * 512 + cb1 + n * 16) ^ SWZ(t);
                SM[idx] = h;
                SM[8192 + idx] = lo;
            }
    }
    __syncthreads();

    // ---- layer 2 + sigmoid -> gate
    const int cb2 = w * 64 + lr;
    f32x4 acc2[4];
#pragma unroll
    for (int n = 0; n < 4; ++n) acc2[n] = (f32x4){0.f, 0.f, 0.f, 0.f};

    for (int k2t = 0; k2t < 16; ++k2t) {
        const int idx = (lr * 512 + k2t * 32 + kg * 8) ^ SWZ(lr);
        const bf16x8 ah = *(const bf16x8*)&SM[idx];
        const bf16x8 al = *(const bf16x8*)&SM[8192 + idx];
#pragma unroll
        for (int n = 0; n < 4; ++n) {
            const size_t wi = ((size_t)((k2t * 4 + kg) * 256) + cb2 + n * 16) * 8;
            const bf16x8 bh = *(const bf16x8*)(w2fh + wi);
            const bf16x8 bl = *(const bf16x8*)(w2fl + wi);
            acc2[n] = __builtin_amdgcn_mfma_f32_16x16x32_bf16(ah, bh, acc2[n], 0, 0, 0);
            acc2[n] = __builtin_amdgcn_mfma_f32_16x16x32_bf16(ah, bl, acc2[n], 0, 0, 0);
            acc2[n] = __builtin_amdgcn_mfma_f32_16x16x32_bf16(al, bh, acc2[n], 0, 0, 0);
        }
    }
    {
#pragma unroll
        for (int n = 0; n < 4; ++n) {
            const float b2v = b2[cb2 + n * 16];
            float4 o;
            o.x = 1.f / (1.f + expf(-(acc2[n][0] + b2v)));
            o.y = 1.f / (1.f + expf(-(acc2[n][1] + b2v)));
            o.z = 1.f / (1.f + expf(-(acc2[n][2] + b2v)));
            o.w = 1.f / (1.f + expf(-(acc2[n][3] + b2v)));
            // tokens kg*4+0..3 are consecutive -> float4 store
            *(float4*)&gate[((size_t)b * 256 + cb2 + n * 16) * 256 + t0 + kg * 4] = o;
        }
    }
}

// ---------------------------------------------------------------- K5: apply alpha/gate + inverse Haar (unchanged)
__global__ __launch_bounds__(256)
void k_final(const float* __restrict__ xb,
             const float* __restrict__ alpha,
             const float* __restrict__ gate,
             float* __restrict__ out)
{
    const int bc    = blockIdx.x >> 3;
    const int ytile = blockIdx.x & 7;
    const int x2 = threadIdx.x & 31;
    const int y  = ytile * 8 + (threadIdx.x >> 5);
    const int b  = bc >> 8;

    const float* p = xb + (size_t)bc * (128 * 128) + (2 * y) * 128 + 4 * x2;
    const float4 r0 = *(const float4*)(p);
    const float4 r1 = *(const float4*)(p + 128);

    const int th = (y >> 1) * 32 + x2;
    const float ah = alpha[(size_t)0 * 16384 + b * 1024 + th];
    const float av = alpha[(size_t)1 * 16384 + b * 1024 + th];
    const float ad = alpha[(size_t)2 * 16384 + b * 1024 + th];
    const float g  = gate[(size_t)bc * 256 + (y >> 2) * 16 + (x2 >> 1)];

    float4 o_top, o_bot;
    {
        const float p00 = r0.x, p01 = r0.y, p10 = r1.x, p11 = r1.y;
        const float a  = 0.25f * (p00 + p01 + p10 + p11) * g;
        const float hb = 0.25f * (p00 - p01 + p10 - p11) * ah;
        const float vb = 0.25f * (p00 + p01 - p10 - p11) * av;
        const float db = 0.25f * (p00 - p01 - p10 + p11) * ad;
        o_top.x = a + hb + vb + db;  o_top.y = a - hb + vb - db;
        o_bot.x = a + hb - vb - db;  o_bot.y = a - hb - vb + db;
    }
    {
        const float p00 = r0.z, p01 = r0.w, p10 = r1.z, p11 = r1.w;
        const float a  = 0.25f * (p00 + p01 + p10 + p11) * g;
        const float hb = 0.25f * (p00 - p01 + p10 - p11) * ah;
        const float vb = 0.25f * (p00 + p01 - p10 - p11) * av;
        const float db = 0.25f * (p00 - p01 - p10 + p11) * ad;
        o_top.z = a + hb + vb + db;  o_top.w = a - hb + vb - db;
        o_bot.z = a + hb - vb - db;  o_bot.w = a - hb - vb + db;
    }
    float* q = out + (size_t)bc * (128 * 128) + (2 * y) * 128 + 4 * x2;
    *(float4*)(q)       = o_top;
    *(float4*)(q + 128) = o_bot;
}

// ---------------------------------------------------------------- launch
extern "C" void kernel_launch(void* const* d_in, const int* in_sizes, int n_in,
                              void* d_out, int out_size, void* d_ws, size_t ws_size,
                              hipStream_t stream)
{
    (void)in_sizes; (void)n_in; (void)out_size; (void)ws_size;
    const float* x_big     = (const float*)d_in[0];
    const float* x_small   = (const float*)d_in[1];
    const float* hf_w1     = (const float*)d_in[2];
    const float* hf_b1     = (const float*)d_in[3];
    const float* hf_ln_w   = (const float*)d_in[4];
    const float* hf_ln_b   = (const float*)d_in[5];
    const float* hf_w2     = (const float*)d_in[6];
    const float* hf_b2     = (const float*)d_in[7];
    const float* hf_prompt = (const float*)d_in[8];
    const float* low_w     = (const float*)d_in[9];
    const float* low_b     = (const float*)d_in[10];
    const float* lf_w1     = (const float*)d_in[11];
    const float* lf_b1     = (const float*)d_in[12];
    const float* lf_ln_w   = (const float*)d_in[13];
    const float* lf_ln_b   = (const float*)d_in[14];
    const float* lf_w2     = (const float*)d_in[15];
    const float* lf_b2     = (const float*)d_in[16];
    float* out = (float*)d_out;

    float* ws    = (float*)d_ws;
    float* z     = ws;                               // 3*4096*1024   = 12,582,912 f
    float* sp    = z + (size_t)3 * 4096 * 1024;      // 16*512*256    =  2,097,152 f
    float* alpha = sp + (size_t)16 * 512 * 256;      // 3*16*1024     =     49,152 f
    float* gate  = alpha + (size_t)3 * 16 * 1024;    // 16*256*256    =  1,048,576 f
    u16* w1fh  = (u16*)(gate + (size_t)16 * 256 * 256);  // 131072 u16 each
    u16* w1fl  = w1fh  + 131072;
    u16* w2fh  = w1fl  + 131072;
    u16* w2fl  = w2fh  + 131072;
    u16* lowfh = w2fl  + 131072;
    u16* lowfl = lowfh + 131072;
    u16* lw1fh = lowfl + 131072;
    u16* lw1fl = lw1fh + 131072;
    u16* lw2fh = lw1fl + 131072;
    u16* lw2fl = lw2fh + 131072;

    k_prep       <<<2048, 256, 0, stream>>>(hf_w1, hf_w2, low_w, lf_w1, lf_w2,
                                            w1fh, w1fl, w2fh, w2fl,
                                            lowfh, lowfl, lw1fh, lw1fl, lw2fh, lw2fl);
    k_haar_tokens<<<4096, 256, 0, stream>>>(x_big, z);
    k_pool_small <<<8192, 256, 0, stream>>>(x_small, sp);
    k_mlp_high   <<<1536, 256, 0, stream>>>(z, w1fh, w1fl, w2fh, w2fl,
                                            hf_b1, hf_ln_w, hf_ln_b, hf_b2, hf_prompt, alpha);
    k_mlp_low    <<<256, 256, 0, stream>>>(sp, lowfh, lowfl, low_b,
                                           lw1fh, lw1fl, lf_b1, lf_ln_w, lf_ln_b,
                                           lw2fh, lw2fl, lf_b2, gate);
    k_final      <<<32768, 256, 0, stream>>>(x_big, alpha, gate, out);
}

// Round 5
// 753.706 us; speedup vs baseline: 1.7704x; 1.1066x over previous
//
#include <hip/hip_runtime.h>
#include <cstdint>
#include <cmath>

typedef unsigned short u16;
typedef __bf16 bf16x8 __attribute__((ext_vector_type(8)));
typedef float f32x4 __attribute__((ext_vector_type(4)));

__device__ __forceinline__ u16 bf16_rne(float v) {
    union { float f; uint32_t u; } a; a.f = v;
    uint32_t r = a.u + 0x7fffu + ((a.u >> 16) & 1u);
    return (u16)(r >> 16);
}
__device__ __forceinline__ float bf16_to_f(u16 h) {
    union { uint32_t u; float f; } a; a.u = ((uint32_t)h) << 16;
    return a.f;
}

// Shapes: B=16, Cb=256, H=W=128 -> h2=w2=64. hid=512. Cs=512.
// hf tokens: 32x32=1024/batch/band, 3 bands -> 49152 tokens, dim 256.
// lf tokens: 16x16=256/batch -> 4096 tokens.

// frag layout (ncol = output cols): [kt][kg(4)][col(ncol)][e(8)], element = W[kt*32+kg*8+e][col]
__device__ __forceinline__ void split_row(const float* __restrict__ src,
                                          u16* __restrict__ dh, u16* __restrict__ dl,
                                          int k, int ncol, int tidx)
{
    const int kt = k >> 5, kg = (k >> 3) & 3, e = k & 7;
    for (int col = tidx; col < ncol; col += 256) {
        const float v = src[(size_t)k * ncol + col];
        const u16 h  = bf16_rne(v);
        const u16 lo = bf16_rne(v - bf16_to_f(h));
        const size_t idx = ((size_t)((kt * 4 + kg) * ncol) + col) * 8 + e;
        dh[idx] = h; dl[idx] = lo;
    }
}

// ---------------------------------------------------------------- K_front: haar tokens | pool | weight prep (fused)
// blocks [0,4096): haar |band| 2x2-mean tokens -> z [band(3)][b*256+c][1024]
// blocks [4096,12288): 4x4 mean pool of x_small -> sp [b*512+s][256]
// blocks [12288,14336): weight hi/lo split
__global__ __launch_bounds__(256)
void k_front(const float* __restrict__ xb, const float* __restrict__ xs,
             const float* __restrict__ w1,  const float* __restrict__ w2,
             const float* __restrict__ low, const float* __restrict__ v1,
             const float* __restrict__ v2,
             float* __restrict__ z, float* __restrict__ sp,
             u16* __restrict__ w1fh,  u16* __restrict__ w1fl,
             u16* __restrict__ w2fh,  u16* __restrict__ w2fl,
             u16* __restrict__ lowfh, u16* __restrict__ lowfl,
             u16* __restrict__ v1fh,  u16* __restrict__ v1fl,
             u16* __restrict__ v2fh,  u16* __restrict__ v2fl)
{
    const int bid = blockIdx.x;
    if (bid < 4096) {
        // ---- haar tokens
        const int bc  = bid;                 // b*256 + c
        const int px  = threadIdx.x & 31;
        const int py0 = threadIdx.x >> 5;    // [0,8)
        const float* base = xb + (size_t)bc * (128 * 128);
#pragma unroll
        for (int s = 0; s < 4; ++s) {
            const int py = py0 + 8 * s;      // [0,32)
            const float* p = base + (4 * py) * 128 + 4 * px;
            const float4 r0 = *(const float4*)(p);
            const float4 r1 = *(const float4*)(p + 128);
            const float4 r2 = *(const float4*)(p + 256);
            const float4 r3 = *(const float4*)(p + 384);
            float zh = 0.f, zv = 0.f, zd = 0.f;
            {
                const float p00 = r0.x, p01 = r0.y, p10 = r1.x, p11 = r1.y;
                zh += fabsf(p00 - p01 + p10 - p11);
                zv += fabsf(p00 + p01 - p10 - p11);
                zd += fabsf(p00 - p01 - p10 + p11);
            }
            {
                const float p00 = r0.z, p01 = r0.w, p10 = r1.z, p11 = r1.w;
                zh += fabsf(p00 - p01 + p10 - p11);
                zv += fabsf(p00 + p01 - p10 - p11);
                zd += fabsf(p00 - p01 - p10 + p11);
            }
            {
                const float p00 = r2.x, p01 = r2.y, p10 = r3.x, p11 = r3.y;
                zh += fabsf(p00 - p01 + p10 - p11);
                zv += fabsf(p00 + p01 - p10 - p11);
                zd += fabsf(p00 - p01 - p10 + p11);
            }
            {
                const float p00 = r2.z, p01 = r2.w, p10 = r3.z, p11 = r3.w;
                zh += fabsf(p00 - p01 + p10 - p11);
                zv += fabsf(p00 + p01 - p10 - p11);
                zd += fabsf(p00 - p01 - p10 + p11);
            }
            const float sc = 0.0625f;
            const int t = py * 32 + px;
            z[(size_t)(0 * 4096 + bc) * 1024 + t] = zh * sc;
            z[(size_t)(1 * 4096 + bc) * 1024 + t] = zv * sc;
            z[(size_t)(2 * 4096 + bc) * 1024 + t] = zd * sc;
        }
    } else if (bid < 12288) {
        // ---- pool small
        const int bs = bid - 4096;           // b*512 + s
        const int px = threadIdx.x & 15;
        const int py = threadIdx.x >> 4;
        const float* p = xs + (size_t)bs * 4096 + (4 * py) * 64 + 4 * px;
        float s = 0.f;
#pragma unroll
        for (int r = 0; r < 4; ++r) {
            const float4 v = *(const float4*)(p + 64 * r);
            s += v.x + v.y + v.z + v.w;
        }
        sp[(size_t)bs * 256 + threadIdx.x] = s * 0.0625f;
    } else {
        // ---- weight prep
        const int pb = bid - 12288;          // [0,2048)
        if      (pb < 256)  split_row(w1,  w1fh,  w1fl,  pb,        512, threadIdx.x);
        else if (pb < 768)  split_row(w2,  w2fh,  w2fl,  pb - 256,  256, threadIdx.x);
        else if (pb < 1280) split_row(low, lowfh, lowfl, pb - 768,  256, threadIdx.x);
        else if (pb < 1536) split_row(v1,  v1fh,  v1fl,  pb - 1280, 512, threadIdx.x);
        else                split_row(v2,  v2fh,  v2fl,  pb - 1536, 256, threadIdx.x);
    }
}

// LDS swizzle: u16-index ^= ((row&7)<<3), applied on write AND read (involution).
#define SWZ(t) (((t) & 7) << 3)

// ---------------------------------------------------------------- K_mlp: fused low path (blocks [0,256)) + hf path (blocks [256,1792))
// All accumulator-indexing loops FULLY unrolled (rule #20: runtime-indexed ext_vector -> scratch).
__global__ __launch_bounds__(256, 2)
void k_mlp(const float* __restrict__ z, const float* __restrict__ sp,
           const u16* __restrict__ w1fh, const u16* __restrict__ w1fl,
           const u16* __restrict__ w2fh, const u16* __restrict__ w2fl,
           const float* __restrict__ b1,
           const float* __restrict__ lnw, const float* __restrict__ lnb,
           const float* __restrict__ b2,
           const float* __restrict__ prompt,
           const u16* __restrict__ lowfh, const u16* __restrict__ lowfl,
           const float* __restrict__ lb_,
           const u16* __restrict__ v1fh, const u16* __restrict__ v1fl,
           const float* __restrict__ c1,
           const float* __restrict__ vlnw, const float* __restrict__ vlnb,
           const u16* __restrict__ v2fh, const u16* __restrict__ v2fl,
           const float* __restrict__ c2,
           float* __restrict__ alpha, float* __restrict__ gate)
{
    __shared__ u16 SM[32768];             // 64KB, shared by both paths
    __shared__ float partA[4][32], partB[4][32];
    __shared__ float partP[4];
    __shared__ float mu_s[32], rs_s[32];

    const int tid = threadIdx.x;
    const int l   = tid & 63;
    const int w   = tid >> 6;
    const int lr  = l & 15;
    const int kg  = l >> 4;

    if (blockIdx.x >= 256) {
        // ================= hf path: 32 tokens/block, 1536 blocks =================
        const int hb   = blockIdx.x - 256;
        const int tile = hb & 31;
        const int bb   = hb >> 5;
        const int t0   = tile * 32;

        // ---- stage Z: global f32 [c][t] -> LDS bf16 hi/lo [t][c] (swizzled)
        {
            const int c = tid;
            const float* src = z + ((size_t)bb * 256 + c) * 1024 + t0;
#pragma unroll
            for (int j = 0; j < 32; j += 4) {
                const float4 v = *(const float4*)(src + j);
                const float vv[4] = {v.x, v.y, v.z, v.w};
#pragma unroll
                for (int q = 0; q < 4; ++q) {
                    const int t = j + q;
                    const u16 h  = bf16_rne(vv[q]);
                    const u16 lo = bf16_rne(vv[q] - bf16_to_f(h));
                    const int idx = (t * 256 + c) ^ SWZ(t);
                    SM[idx] = h;
                    SM[8192 + idx] = lo;
                }
            }
        }
        __syncthreads();

        // ---- layer 1: D[32 tok x 512 hid] = Z[32x256] @ W1, split-bf16 (hh + hl + lh)
        const int cb1 = w * 128 + lr;
        f32x4 acc[2][8];
#pragma unroll
        for (int m = 0; m < 2; ++m)
#pragma unroll
            for (int n = 0; n < 8; ++n) acc[m][n] = (f32x4){0.f, 0.f, 0.f, 0.f};

        for (int kt = 0; kt < 8; ++kt) {
            bf16x8 ah[2], al[2];
#pragma unroll
            for (int m = 0; m < 2; ++m) {
                const int idx = ((m * 16 + lr) * 256 + kt * 32 + kg * 8) ^ SWZ(lr);
                ah[m] = *(const bf16x8*)&SM[idx];
                al[m] = *(const bf16x8*)&SM[8192 + idx];
            }
#pragma unroll
            for (int n = 0; n < 8; ++n) {
                const size_t wi = ((size_t)((kt * 4 + kg) * 512) + cb1 + n * 16) * 8;
                const bf16x8 bh = *(const bf16x8*)(w1fh + wi);
                const bf16x8 bl = *(const bf16x8*)(w1fl + wi);
#pragma unroll
                for (int m = 0; m < 2; ++m) acc[m][n] = __builtin_amdgcn_mfma_f32_16x16x32_bf16(ah[m], bh, acc[m][n], 0, 0, 0);
#pragma unroll
                for (int m = 0; m < 2; ++m) acc[m][n] = __builtin_amdgcn_mfma_f32_16x16x32_bf16(ah[m], bl, acc[m][n], 0, 0, 0);
#pragma unroll
                for (int m = 0; m < 2; ++m) acc[m][n] = __builtin_amdgcn_mfma_f32_16x16x32_bf16(al[m], bh, acc[m][n], 0, 0, 0);
            }
        }

        // ---- + b1, LN stats (cross-wave)
        float b1v[8];
#pragma unroll
        for (int n = 0; n < 8; ++n) b1v[n] = b1[cb1 + n * 16];
#pragma unroll
        for (int m = 0; m < 2; ++m)
#pragma unroll
            for (int n = 0; n < 8; ++n)
#pragma unroll
                for (int i = 0; i < 4; ++i) acc[m][n][i] += b1v[n];

#pragma unroll
        for (int m = 0; m < 2; ++m) {
            f32x4 s = (f32x4){0.f,0.f,0.f,0.f}, ss = (f32x4){0.f,0.f,0.f,0.f};
#pragma unroll
            for (int n = 0; n < 8; ++n)
#pragma unroll
                for (int i = 0; i < 4; ++i) { s[i] += acc[m][n][i]; ss[i] = fmaf(acc[m][n][i], acc[m][n][i], ss[i]); }
#pragma unroll
            for (int msk = 1; msk < 16; msk <<= 1) {
#pragma unroll
                for (int i = 0; i < 4; ++i) { s[i] += __shfl_xor(s[i], msk); ss[i] += __shfl_xor(ss[i], msk); }
            }
            if (lr == 0) {
#pragma unroll
                for (int i = 0; i < 4; ++i) {
                    partA[w][m * 16 + kg * 4 + i] = s[i];
                    partB[w][m * 16 + kg * 4 + i] = ss[i];
                }
            }
        }
        __syncthreads();
        if (tid < 32) {
            const float s  = partA[0][tid] + partA[1][tid] + partA[2][tid] + partA[3][tid];
            const float ss = partB[0][tid] + partB[1][tid] + partB[2][tid] + partB[3][tid];
            const float mu  = s * (1.f / 512.f);
            const float var = ss * (1.f / 512.f) - mu * mu;
            mu_s[tid] = mu;
            rs_s[tid] = rsqrtf(var + 1e-5f);
        }
        __syncthreads();

        // ---- publish LN'd H (hi/lo bf16) into SM (overwrites Z region)
        {
            float lwv[8], lbv[8];
#pragma unroll
            for (int n = 0; n < 8; ++n) { lwv[n] = lnw[cb1 + n * 16]; lbv[n] = lnb[cb1 + n * 16]; }
#pragma unroll
            for (int m = 0; m < 2; ++m)
#pragma unroll
                for (int n = 0; n < 8; ++n)
#pragma unroll
                    for (int i = 0; i < 4; ++i) {
                        const int t = m * 16 + kg * 4 + i;
                        const float v = (acc[m][n][i] - mu_s[t]) * rs_s[t] * lwv[n] + lbv[n];
                        const u16 h  = bf16_rne(v);
                        const u16 lo = bf16_rne(v - bf16_to_f(h));
                        const int col = cb1 + n * 16;
                        const int idx = (t * 512 + col) ^ SWZ(t);
                        SM[idx] = h;
                        SM[16384 + idx] = lo;
                    }
        }
        __syncthreads();

        // ---- layer 2: q[32 tok x 256] = H[32x512] @ W2, split-bf16
        const int cb2 = w * 64 + lr;
        f32x4 acc2[2][4];
#pragma unroll
        for (int m = 0; m < 2; ++m)
#pragma unroll
            for (int n = 0; n < 4; ++n) acc2[m][n] = (f32x4){0.f, 0.f, 0.f, 0.f};

        for (int k2t = 0; k2t < 16; ++k2t) {
            bf16x8 ah[2], al[2];
#pragma unroll
            for (int m = 0; m < 2; ++m) {
                const int idx = ((m * 16 + lr) * 512 + k2t * 32 + kg * 8) ^ SWZ(lr);
                ah[m] = *(const bf16x8*)&SM[idx];
                al[m] = *(const bf16x8*)&SM[16384 + idx];
            }
#pragma unroll
            for (int n = 0; n < 4; ++n) {
                const size_t wi = ((size_t)((k2t * 4 + kg) * 256) + cb2 + n * 16) * 8;
                const bf16x8 bh = *(const bf16x8*)(w2fh + wi);
                const bf16x8 bl = *(const bf16x8*)(w2fl + wi);
#pragma unroll
                for (int m = 0; m < 2; ++m) acc2[m][n] = __builtin_amdgcn_mfma_f32_16x16x32_bf16(ah[m], bh, acc2[m][n], 0, 0, 0);
#pragma unroll
                for (int m = 0; m < 2; ++m) acc2[m][n] = __builtin_amdgcn_mfma_f32_16x16x32_bf16(ah[m], bl, acc2[m][n], 0, 0, 0);
#pragma unroll
                for (int m = 0; m < 2; ++m) acc2[m][n] = __builtin_amdgcn_mfma_f32_16x16x32_bf16(al[m], bh, acc2[m][n], 0, 0, 0);
            }
        }

        // ---- cosine head
        float b2v[4], prv[4];
#pragma unroll
        for (int n = 0; n < 4; ++n) { b2v[n] = b2[cb2 + n * 16]; prv[n] = prompt[cb2 + n * 16]; }
        {
            float pp = 0.f;
#pragma unroll
            for (int n = 0; n < 4; ++n) pp = fmaf(prv[n], prv[n], pp);
#pragma unroll
            for (int msk = 1; msk < 16; msk <<= 1) pp += __shfl_xor(pp, msk);
            if (l == 0) partP[w] = pp;
        }
#pragma unroll
        for (int m = 0; m < 2; ++m) {
            f32x4 dt = (f32x4){0.f,0.f,0.f,0.f}, nn = (f32x4){0.f,0.f,0.f,0.f};
#pragma unroll
            for (int n = 0; n < 4; ++n)
#pragma unroll
                for (int i = 0; i < 4; ++i) {
                    const float q = acc2[m][n][i] + b2v[n];
                    dt[i] = fmaf(q, prv[n], dt[i]);
                    nn[i] = fmaf(q, q, nn[i]);
                }
#pragma unroll
            for (int msk = 1; msk < 16; msk <<= 1) {
#pragma unroll
                for (int i = 0; i < 4; ++i) { dt[i] += __shfl_xor(dt[i], msk); nn[i] += __shfl_xor(nn[i], msk); }
            }
            if (lr == 0) {
#pragma unroll
                for (int i = 0; i < 4; ++i) {
                    partA[w][m * 16 + kg * 4 + i] = dt[i];
                    partB[w][m * 16 + kg * 4 + i] = nn[i];
                }
            }
        }
        __syncthreads();
        if (tid < 32) {
            const float dot = partA[0][tid] + partA[1][tid] + partA[2][tid] + partA[3][tid];
            const float nq2 = partB[0][tid] + partB[1][tid] + partB[2][tid] + partB[3][tid];
            const float ppt = partP[0] + partP[1] + partP[2] + partP[3];
            const float nq  = fmaxf(sqrtf(nq2), 1e-8f);
            const float npr = fmaxf(sqrtf(ppt), 1e-8f);
            alpha[(size_t)bb * 1024 + t0 + tid] = fmaxf(dot / (nq * npr), 0.f);
        }
    } else {
        // ================= low path: 16 tokens/block, 256 blocks =================
        const int tile = blockIdx.x & 15;
        const int b    = blockIdx.x >> 4;
        const int t0   = tile * 16;

        // ---- stage sp tile: global f32 [s][t] -> LDS bf16 hi/lo [t][s] (swizzled)
#pragma unroll
        for (int hh = 0; hh < 2; ++hh) {
            const int s = tid + hh * 256;
            const float* src = sp + ((size_t)b * 512 + s) * 256 + t0;
#pragma unroll
            for (int j = 0; j < 16; j += 4) {
                const float4 v = *(const float4*)(src + j);
                const float vv[4] = {v.x, v.y, v.z, v.w};
#pragma unroll
                for (int q = 0; q < 4; ++q) {
                    const int t = j + q;
                    const u16 h  = bf16_rne(vv[q]);
                    const u16 lo = bf16_rne(vv[q] - bf16_to_f(h));
                    const int idx = (t * 512 + s) ^ SWZ(t);
                    SM[idx] = h;
                    SM[8192 + idx] = lo;
                }
            }
        }
        __syncthreads();

        // ---- phase A: k_tok[16 x 256] = spT[16x512] @ low_w, split-bf16
        const int cbA = w * 64 + lr;
        f32x4 accA[4];
#pragma unroll
        for (int n = 0; n < 4; ++n) accA[n] = (f32x4){0.f, 0.f, 0.f, 0.f};

        for (int kt = 0; kt < 16; ++kt) {
            const int idx = (lr * 512 + kt * 32 + kg * 8) ^ SWZ(lr);
            const bf16x8 ah = *(const bf16x8*)&SM[idx];
            const bf16x8 al = *(const bf16x8*)&SM[8192 + idx];
#pragma unroll
            for (int n = 0; n < 4; ++n) {
                const size_t wi = ((size_t)((kt * 4 + kg) * 256) + cbA + n * 16) * 8;
                const bf16x8 bh = *(const bf16x8*)(lowfh + wi);
                const bf16x8 bl = *(const bf16x8*)(lowfl + wi);
                accA[n] = __builtin_amdgcn_mfma_f32_16x16x32_bf16(ah, bh, accA[n], 0, 0, 0);
                accA[n] = __builtin_amdgcn_mfma_f32_16x16x32_bf16(ah, bl, accA[n], 0, 0, 0);
                accA[n] = __builtin_amdgcn_mfma_f32_16x16x32_bf16(al, bh, accA[n], 0, 0, 0);
            }
        }
        __syncthreads();      // all sp reads done

        // ---- publish k_tok (hi/lo bf16) into SM[0..8191]
        {
            float lbv[4];
#pragma unroll
            for (int n = 0; n < 4; ++n) lbv[n] = lb_[cbA + n * 16];
#pragma unroll
            for (int n = 0; n < 4; ++n)
#pragma unroll
                for (int i = 0; i < 4; ++i) {
                    const int t = kg * 4 + i;
                    const float v = accA[n][i] + lbv[n];
                    const u16 h  = bf16_rne(v);
                    const u16 lo = bf16_rne(v - bf16_to_f(h));
                    const int idx = (t * 256 + cbA + n * 16) ^ SWZ(t);
                    SM[idx] = h;
                    SM[4096 + idx] = lo;
                }
        }
        __syncthreads();

        // ---- layer 1: D[16 tok x 512 hid] = K[16x256] @ V1, split-bf16
        const int cb1 = w * 128 + lr;
        f32x4 acc1[8];
#pragma unroll
        for (int n = 0; n < 8; ++n) acc1[n] = (f32x4){0.f, 0.f, 0.f, 0.f};

        for (int kt = 0; kt < 8; ++kt) {
            const int idx = (lr * 256 + kt * 32 + kg * 8) ^ SWZ(lr);
            const bf16x8 ah = *(const bf16x8*)&SM[idx];
            const bf16x8 al = *(const bf16x8*)&SM[4096 + idx];
#pragma unroll
            for (int n = 0; n < 8; ++n) {
                const size_t wi = ((size_t)((kt * 4 + kg) * 512) + cb1 + n * 16) * 8;
                const bf16x8 bh = *(const bf16x8*)(v1fh + wi);
                const bf16x8 bl = *(const bf16x8*)(v1fl + wi);
                acc1[n] = __builtin_amdgcn_mfma_f32_16x16x32_bf16(ah, bh, acc1[n], 0, 0, 0);
                acc1[n] = __builtin_amdgcn_mfma_f32_16x16x32_bf16(ah, bl, acc1[n], 0, 0, 0);
                acc1[n] = __builtin_amdgcn_mfma_f32_16x16x32_bf16(al, bh, acc1[n], 0, 0, 0);
            }
        }

        // ---- + c1, LN stats
        {
            float b1v[8];
#pragma unroll
            for (int n = 0; n < 8; ++n) b1v[n] = c1[cb1 + n * 16];
#pragma unroll
            for (int n = 0; n < 8; ++n)
#pragma unroll
                for (int i = 0; i < 4; ++i) acc1[n][i] += b1v[n];

            f32x4 s = (f32x4){0.f,0.f,0.f,0.f}, ss = (f32x4){0.f,0.f,0.f,0.f};
#pragma unroll
            for (int n = 0; n < 8; ++n)
#pragma unroll
                for (int i = 0; i < 4; ++i) { s[i] += acc1[n][i]; ss[i] = fmaf(acc1[n][i], acc1[n][i], ss[i]); }
#pragma unroll
            for (int msk = 1; msk < 16; msk <<= 1) {
#pragma unroll
                for (int i = 0; i < 4; ++i) { s[i] += __shfl_xor(s[i], msk); ss[i] += __shfl_xor(ss[i], msk); }
            }
            if (lr == 0) {
#pragma unroll
                for (int i = 0; i < 4; ++i) {
                    partA[w][kg * 4 + i] = s[i];
                    partB[w][kg * 4 + i] = ss[i];
                }
            }
        }
        __syncthreads();
        if (tid < 16) {
            const float s  = partA[0][tid] + partA[1][tid] + partA[2][tid] + partA[3][tid];
            const float ss = partB[0][tid] + partB[1][tid] + partB[2][tid] + partB[3][tid];
            const float mu  = s * (1.f / 512.f);
            const float var = ss * (1.f / 512.f) - mu * mu;
            mu_s[tid] = mu;
            rs_s[tid] = rsqrtf(var + 1e-5f);
        }
        __syncthreads();

        // ---- publish LN'd H (hi/lo bf16) into SM (overwrites k_tok)
        {
            float lwv[8], lbv[8];
#pragma unroll
            for (int n = 0; n < 8; ++n) { lwv[n] = vlnw[cb1 + n * 16]; lbv[n] = vlnb[cb1 + n * 16]; }
#pragma unroll
            for (int n = 0; n < 8; ++n)
#pragma unroll
                for (int i = 0; i < 4; ++i) {
                    const int t = kg * 4 + i;
                    const float v = (acc1[n][i] - mu_s[t]) * rs_s[t] * lwv[n] + lbv[n];
                    const u16 h  = bf16_rne(v);
                    const u16 lo = bf16_rne(v - bf16_to_f(h));
                    const int idx = (t * 512 + cb1 + n * 16) ^ SWZ(t);
                    SM[idx] = h;
                    SM[8192 + idx] = lo;
                }
        }
        __syncthreads();

        // ---- layer 2 + sigmoid -> gate
        const int cb2 = w * 64 + lr;
        f32x4 acc2[4];
#pragma unroll
        for (int n = 0; n < 4; ++n) acc2[n] = (f32x4){0.f, 0.f, 0.f, 0.f};

        for (int k2t = 0; k2t < 16; ++k2t) {
            const int idx = (lr * 512 + k2t * 32 + kg * 8) ^ SWZ(lr);
            const bf16x8 ah = *(const bf16x8*)&SM[idx];
            const bf16x8 al = *(const bf16x8*)&SM[8192 + idx];
#pragma unroll
            for (int n = 0; n < 4; ++n) {
                const size_t wi = ((size_t)((k2t * 4 + kg) * 256) + cb2 + n * 16) * 8;
                const bf16x8 bh = *(const bf16x8*)(v2fh + wi);
                const bf16x8 bl = *(const bf16x8*)(v2fl + wi);
                acc2[n] = __builtin_amdgcn_mfma_f32_16x16x32_bf16(ah, bh, acc2[n], 0, 0, 0);
                acc2[n] = __builtin_amdgcn_mfma_f32_16x16x32_bf16(ah, bl, acc2[n], 0, 0, 0);
                acc2[n] = __builtin_amdgcn_mfma_f32_16x16x32_bf16(al, bh, acc2[n], 0, 0, 0);
            }
        }
        {
#pragma unroll
            for (int n = 0; n < 4; ++n) {
                const float b2v = c2[cb2 + n * 16];
                float4 o;
                o.x = 1.f / (1.f + expf(-(acc2[n][0] + b2v)));
                o.y = 1.f / (1.f + expf(-(acc2[n][1] + b2v)));
                o.z = 1.f / (1.f + expf(-(acc2[n][2] + b2v)));
                o.w = 1.f / (1.f + expf(-(acc2[n][3] + b2v)));
                *(float4*)&gate[((size_t)b * 256 + cb2 + n * 16) * 256 + t0 + kg * 4] = o;
            }
        }
    }
}

// ---------------------------------------------------------------- K_final: apply alpha/gate + inverse Haar
__global__ __launch_bounds__(256)
void k_final(const float* __restrict__ xb,
             const float* __restrict__ alpha,
             const float* __restrict__ gate,
             float* __restrict__ out)
{
    const int bc    = blockIdx.x >> 3;
    const int ytile = blockIdx.x & 7;
    const int x2 = threadIdx.x & 31;
    const int y  = ytile * 8 + (threadIdx.x >> 5);
    const int b  = bc >> 8;

    const float* p = xb + (size_t)bc * (128 * 128) + (2 * y) * 128 + 4 * x2;
    const float4 r0 = *(const float4*)(p);
    const float4 r1 = *(const float4*)(p + 128);

    const int th = (y >> 1) * 32 + x2;
    const float ah = alpha[(size_t)0 * 16384 + b * 1024 + th];
    const float av = alpha[(size_t)1 * 16384 + b * 1024 + th];
    const float ad = alpha[(size_t)2 * 16384 + b * 1024 + th];
    const float g  = gate[(size_t)bc * 256 + (y >> 2) * 16 + (x2 >> 1)];

    float4 o_top, o_bot;
    {
        const float p00 = r0.x, p01 = r0.y, p10 = r1.x, p11 = r1.y;
        const float a  = 0.25f * (p00 + p01 + p10 + p11) * g;
        const float hb = 0.25f * (p00 - p01 + p10 - p11) * ah;
        const float vb = 0.25f * (p00 + p01 - p10 - p11) * av;
        const float db = 0.25f * (p00 - p01 - p10 + p11) * ad;
        o_top.x = a + hb + vb + db;  o_top.y = a - hb + vb - db;
        o_bot.x = a + hb - vb - db;  o_bot.y = a - hb - vb + db;
    }
    {
        const float p00 = r0.z, p01 = r0.w, p10 = r1.z, p11 = r1.w;
        const float a  = 0.25f * (p00 + p01 + p10 + p11) * g;
        const float hb = 0.25f * (p00 - p01 + p10 - p11) * ah;
        const float vb = 0.25f * (p00 + p01 - p10 - p11) * av;
        const float db = 0.25f * (p00 - p01 - p10 + p11) * ad;
        o_top.z = a + hb + vb + db;  o_top.w = a - hb + vb - db;
        o_bot.z = a + hb - vb - db;  o_bot.w = a - hb - vb + db;
    }
    float* q = out + (size_t)bc * (128 * 128) + (2 * y) * 128 + 4 * x2;
    *(float4*)(q)       = o_top;
    *(float4*)(q + 128) = o_bot;
}

// ---------------------------------------------------------------- launch
extern "C" void kernel_launch(void* const* d_in, const int* in_sizes, int n_in,
                              void* d_out, int out_size, void* d_ws, size_t ws_size,
                              hipStream_t stream)
{
    (void)in_sizes; (void)n_in; (void)out_size; (void)ws_size;
    const float* x_big     = (const float*)d_in[0];
    const float* x_small   = (const float*)d_in[1];
    const float* hf_w1     = (const float*)d_in[2];
    const float* hf_b1     = (const float*)d_in[3];
    const float* hf_ln_w   = (const float*)d_in[4];
    const float* hf_ln_b   = (const float*)d_in[5];
    const float* hf_w2     = (const float*)d_in[6];
    const float* hf_b2     = (const float*)d_in[7];
    const float* hf_prompt = (const float*)d_in[8];
    const float* low_w     = (const float*)d_in[9];
    const float* low_b     = (const float*)d_in[10];
    const float* lf_w1     = (const float*)d_in[11];
    const float* lf_b1     = (const float*)d_in[12];
    const float* lf_ln_w   = (const float*)d_in[13];
    const float* lf_ln_b   = (const float*)d_in[14];
    const float* lf_w2     = (const float*)d_in[15];
    const float* lf_b2     = (const float*)d_in[16];
    float* out = (float*)d_out;

    float* ws    = (float*)d_ws;
    float* z     = ws;                               // 3*4096*1024   = 12,582,912 f
    float* sp    = z + (size_t)3 * 4096 * 1024;      // 16*512*256    =  2,097,152 f
    float* alpha = sp + (size_t)16 * 512 * 256;      // 3*16*1024     =     49,152 f
    float* gate  = alpha + (size_t)3 * 16 * 1024;    // 16*256*256    =  1,048,576 f
    u16* w1fh  = (u16*)(gate + (size_t)16 * 256 * 256);  // 131072 u16 each
    u16* w1fl  = w1fh  + 131072;
    u16* w2fh  = w1fl  + 131072;
    u16* w2fl  = w2fh  + 131072;
    u16* lowfh = w2fl  + 131072;
    u16* lowfl = lowfh + 131072;
    u16* lw1fh = lowfl + 131072;
    u16* lw1fl = lw1fh + 131072;
    u16* lw2fh = lw1fl + 131072;
    u16* lw2fl = lw2fh + 131072;

    k_front<<<14336, 256, 0, stream>>>(x_big, x_small,
                                       hf_w1, hf_w2, low_w, lf_w1, lf_w2,
                                       z, sp,
                                       w1fh, w1fl, w2fh, w2fl,
                                       lowfh, lowfl, lw1fh, lw1fl, lw2fh, lw2fl);
    k_mlp  <<<1792, 256, 0, stream>>>(z, sp,
                                      w1fh, w1fl, w2fh, w2fl,
                                      hf_b1, hf_ln_w, hf_ln_b, hf_b2, hf_prompt,
                                      lowfh, lowfl, low_b,
                                      lw1fh, lw1fl, lf_b1, lf_ln_w, lf_ln_b,
                                      lw2fh, lw2fl, lf_b2,
                                      alpha, gate);
    k_final<<<32768, 256, 0, stream>>>(x_big, alpha, gate, out);
}

// Round 6
// 712.483 us; speedup vs baseline: 1.8728x; 1.0579x over previous
//
#include <hip/hip_runtime.h>
#include <cstdint>
#include <cmath>

typedef unsigned short u16;
typedef __bf16 bf16x8 __attribute__((ext_vector_type(8)));
typedef float f32x4 __attribute__((ext_vector_type(4)));

__device__ __forceinline__ u16 bf16_rne(float v) {
    union { float f; uint32_t u; } a; a.f = v;
    uint32_t r = a.u + 0x7fffu + ((a.u >> 16) & 1u);
    return (u16)(r >> 16);
}
__device__ __forceinline__ float bf16_to_f(u16 h) {
    union { uint32_t u; float f; } a; a.u = ((uint32_t)h) << 16;
    return a.f;
}
__device__ __forceinline__ uint32_t pack_pair(float v0, float v1, uint32_t& lopack) {
    const u16 h0 = bf16_rne(v0), h1 = bf16_rne(v1);
    const u16 l0 = bf16_rne(v0 - bf16_to_f(h0)), l1 = bf16_rne(v1 - bf16_to_f(h1));
    lopack = (uint32_t)l0 | ((uint32_t)l1 << 16);
    return (uint32_t)h0 | ((uint32_t)h1 << 16);
}

// Shapes: B=16, Cb=256, H=W=128 -> h2=w2=64. hid=512. Cs=512.
// hf tokens: 32x32=1024/batch/band, 3 bands -> 49152 tokens, dim 256.
// lf tokens: 16x16=256/batch -> 4096 tokens.

// frag layout (ncol = output cols): [kt][kg(4)][col(ncol)][e(8)], element = W[kt*32+kg*8+e][col]
__device__ __forceinline__ void split_row(const float* __restrict__ src,
                                          u16* __restrict__ dh, u16* __restrict__ dl,
                                          int k, int ncol, int tidx)
{
    const int kt = k >> 5, kg = (k >> 3) & 3, e = k & 7;
    for (int col = tidx; col < ncol; col += 256) {
        const float v = src[(size_t)k * ncol + col];
        const u16 h  = bf16_rne(v);
        const u16 lo = bf16_rne(v - bf16_to_f(h));
        const size_t idx = ((size_t)((kt * 4 + kg) * ncol) + col) * 8 + e;
        dh[idx] = h; dl[idx] = lo;
    }
}

// ---------------------------------------------------------------- K_front: haar tokens | pool | weight prep (fused)
__global__ __launch_bounds__(256)
void k_front(const float* __restrict__ xb, const float* __restrict__ xs,
             const float* __restrict__ w1,  const float* __restrict__ w2,
             const float* __restrict__ low, const float* __restrict__ v1,
             const float* __restrict__ v2,
             float* __restrict__ z, float* __restrict__ sp,
             u16* __restrict__ w1fh,  u16* __restrict__ w1fl,
             u16* __restrict__ w2fh,  u16* __restrict__ w2fl,
             u16* __restrict__ lowfh, u16* __restrict__ lowfl,
             u16* __restrict__ v1fh,  u16* __restrict__ v1fl,
             u16* __restrict__ v2fh,  u16* __restrict__ v2fl)
{
    const int bid = blockIdx.x;
    if (bid < 4096) {
        // ---- haar tokens
        const int bc  = bid;                 // b*256 + c
        const int px  = threadIdx.x & 31;
        const int py0 = threadIdx.x >> 5;    // [0,8)
        const float* base = xb + (size_t)bc * (128 * 128);
#pragma unroll
        for (int s = 0; s < 4; ++s) {
            const int py = py0 + 8 * s;      // [0,32)
            const float* p = base + (4 * py) * 128 + 4 * px;
            const float4 r0 = *(const float4*)(p);
            const float4 r1 = *(const float4*)(p + 128);
            const float4 r2 = *(const float4*)(p + 256);
            const float4 r3 = *(const float4*)(p + 384);
            float zh = 0.f, zv = 0.f, zd = 0.f;
            {
                const float p00 = r0.x, p01 = r0.y, p10 = r1.x, p11 = r1.y;
                zh += fabsf(p00 - p01 + p10 - p11);
                zv += fabsf(p00 + p01 - p10 - p11);
                zd += fabsf(p00 - p01 - p10 + p11);
            }
            {
                const float p00 = r0.z, p01 = r0.w, p10 = r1.z, p11 = r1.w;
                zh += fabsf(p00 - p01 + p10 - p11);
                zv += fabsf(p00 + p01 - p10 - p11);
                zd += fabsf(p00 - p01 - p10 + p11);
            }
            {
                const float p00 = r2.x, p01 = r2.y, p10 = r3.x, p11 = r3.y;
                zh += fabsf(p00 - p01 + p10 - p11);
                zv += fabsf(p00 + p01 - p10 - p11);
                zd += fabsf(p00 - p01 - p10 + p11);
            }
            {
                const float p00 = r2.z, p01 = r2.w, p10 = r3.z, p11 = r3.w;
                zh += fabsf(p00 - p01 + p10 - p11);
                zv += fabsf(p00 + p01 - p10 - p11);
                zd += fabsf(p00 - p01 - p10 + p11);
            }
            const float sc = 0.0625f;
            const int t = py * 32 + px;
            z[(size_t)(0 * 4096 + bc) * 1024 + t] = zh * sc;
            z[(size_t)(1 * 4096 + bc) * 1024 + t] = zv * sc;
            z[(size_t)(2 * 4096 + bc) * 1024 + t] = zd * sc;
        }
    } else if (bid < 12288) {
        // ---- pool small
        const int bs = bid - 4096;           // b*512 + s
        const int px = threadIdx.x & 15;
        const int py = threadIdx.x >> 4;
        const float* p = xs + (size_t)bs * 4096 + (4 * py) * 64 + 4 * px;
        float s = 0.f;
#pragma unroll
        for (int r = 0; r < 4; ++r) {
            const float4 v = *(const float4*)(p + 64 * r);
            s += v.x + v.y + v.z + v.w;
        }
        sp[(size_t)bs * 256 + threadIdx.x] = s * 0.0625f;
    } else {
        // ---- weight prep
        const int pb = bid - 12288;          // [0,2048)
        if      (pb < 256)  split_row(w1,  w1fh,  w1fl,  pb,        512, threadIdx.x);
        else if (pb < 768)  split_row(w2,  w2fh,  w2fl,  pb - 256,  256, threadIdx.x);
        else if (pb < 1280) split_row(low, lowfh, lowfl, pb - 768,  256, threadIdx.x);
        else if (pb < 1536) split_row(v1,  v1fh,  v1fl,  pb - 1280, 512, threadIdx.x);
        else                split_row(v2,  v2fh,  v2fl,  pb - 1536, 256, threadIdx.x);
    }
}

// LDS swizzle: u16-index ^= ((row&7)<<3), applied on write AND read (involution).
#define SWZ(t) (((t) & 7) << 3)

// ---------------------------------------------------------------- K_mlp: fused low path (blocks [0,256)) + hf path (blocks [256,1792))
// All accumulator-indexing loops FULLY unrolled (rule #20).
// MFMA inner loops: preload ALL B hi/lo fragments, then 3 groups of independent MFMAs
// (chain reuse distance = group width > MFMA latency; was 3 back-to-back dependent ops).
__global__ __launch_bounds__(256, 2)
void k_mlp(const float* __restrict__ z, const float* __restrict__ sp,
           const u16* __restrict__ w1fh, const u16* __restrict__ w1fl,
           const u16* __restrict__ w2fh, const u16* __restrict__ w2fl,
           const float* __restrict__ b1,
           const float* __restrict__ lnw, const float* __restrict__ lnb,
           const float* __restrict__ b2,
           const float* __restrict__ prompt,
           const u16* __restrict__ lowfh, const u16* __restrict__ lowfl,
           const float* __restrict__ lb_,
           const u16* __restrict__ v1fh, const u16* __restrict__ v1fl,
           const float* __restrict__ c1,
           const float* __restrict__ vlnw, const float* __restrict__ vlnb,
           const u16* __restrict__ v2fh, const u16* __restrict__ v2fl,
           const float* __restrict__ c2,
           float* __restrict__ alpha, float* __restrict__ gate)
{
    __shared__ uint32_t SM32[16384];      // 64KB, u16-addressed via SM
    __shared__ float partA[4][32], partB[4][32];
    __shared__ float partP[4];
    __shared__ float mu_s[32], rs_s[32];
    u16* SM = (u16*)SM32;

    const int tid = threadIdx.x;
    const int l   = tid & 63;
    const int w   = tid >> 6;
    const int lr  = l & 15;
    const int kg  = l >> 4;

    if (blockIdx.x >= 256) {
        // ================= hf path: 32 tokens/block, 1536 blocks =================
        const int hb   = blockIdx.x - 256;
        const int tile = hb & 31;
        const int bb   = hb >> 5;
        const int t0   = tile * 32;

        // ---- stage Z: global f32 [c][t] -> LDS bf16 hi/lo [t][c], packed u32 writes
        {
            const int c  = (tid & 127) * 2;         // even column
            const int th = (tid >> 7) * 16;         // token half
            const float* src0 = z + ((size_t)bb * 256 + c) * 1024 + t0 + th;
            const float* src1 = src0 + 1024;
#pragma unroll
            for (int j = 0; j < 16; j += 4) {
                const float4 v0 = *(const float4*)(src0 + j);
                const float4 v1 = *(const float4*)(src1 + j);
                const float a0[4] = {v0.x, v0.y, v0.z, v0.w};
                const float a1[4] = {v1.x, v1.y, v1.z, v1.w};
#pragma unroll
                for (int q = 0; q < 4; ++q) {
                    const int t = th + j + q;
                    uint32_t lp;
                    const uint32_t hp = pack_pair(a0[q], a1[q], lp);
                    const uint32_t idx32 = (uint32_t)(((t * 256 + c) ^ SWZ(t)) >> 1);
                    SM32[idx32]        = hp;
                    SM32[4096 + idx32] = lp;
                }
            }
        }
        __syncthreads();

        // ---- layer 1: D[32 tok x 512 hid] = Z[32x256] @ W1, split-bf16 (hh + hl + lh)
        const int cb1 = w * 128 + lr;
        f32x4 acc[2][8];
#pragma unroll
        for (int m = 0; m < 2; ++m)
#pragma unroll
            for (int n = 0; n < 8; ++n) acc[m][n] = (f32x4){0.f, 0.f, 0.f, 0.f};

        for (int kt = 0; kt < 8; ++kt) {
            bf16x8 ah[2], al[2];
#pragma unroll
            for (int m = 0; m < 2; ++m) {
                const int idx = ((m * 16 + lr) * 256 + kt * 32 + kg * 8) ^ SWZ(lr);
                ah[m] = *(const bf16x8*)&SM[idx];
                al[m] = *(const bf16x8*)&SM[8192 + idx];
            }
            const size_t wb = ((size_t)((kt * 4 + kg) * 512) + cb1) * 8;
            bf16x8 bh[8], bl[8];
#pragma unroll
            for (int n = 0; n < 8; ++n) bh[n] = *(const bf16x8*)(w1fh + wb + n * 128);
#pragma unroll
            for (int n = 0; n < 8; ++n) bl[n] = *(const bf16x8*)(w1fl + wb + n * 128);
#pragma unroll
            for (int n = 0; n < 8; ++n)
#pragma unroll
                for (int m = 0; m < 2; ++m) acc[m][n] = __builtin_amdgcn_mfma_f32_16x16x32_bf16(ah[m], bh[n], acc[m][n], 0, 0, 0);
#pragma unroll
            for (int n = 0; n < 8; ++n)
#pragma unroll
                for (int m = 0; m < 2; ++m) acc[m][n] = __builtin_amdgcn_mfma_f32_16x16x32_bf16(ah[m], bl[n], acc[m][n], 0, 0, 0);
#pragma unroll
            for (int n = 0; n < 8; ++n)
#pragma unroll
                for (int m = 0; m < 2; ++m) acc[m][n] = __builtin_amdgcn_mfma_f32_16x16x32_bf16(al[m], bh[n], acc[m][n], 0, 0, 0);
        }

        // ---- + b1, LN stats (cross-wave)
        float b1v[8];
#pragma unroll
        for (int n = 0; n < 8; ++n) b1v[n] = b1[cb1 + n * 16];
#pragma unroll
        for (int m = 0; m < 2; ++m)
#pragma unroll
            for (int n = 0; n < 8; ++n)
#pragma unroll
                for (int i = 0; i < 4; ++i) acc[m][n][i] += b1v[n];

#pragma unroll
        for (int m = 0; m < 2; ++m) {
            f32x4 s = (f32x4){0.f,0.f,0.f,0.f}, ss = (f32x4){0.f,0.f,0.f,0.f};
#pragma unroll
            for (int n = 0; n < 8; ++n)
#pragma unroll
                for (int i = 0; i < 4; ++i) { s[i] += acc[m][n][i]; ss[i] = fmaf(acc[m][n][i], acc[m][n][i], ss[i]); }
#pragma unroll
            for (int msk = 1; msk < 16; msk <<= 1) {
#pragma unroll
                for (int i = 0; i < 4; ++i) { s[i] += __shfl_xor(s[i], msk); ss[i] += __shfl_xor(ss[i], msk); }
            }
            if (lr == 0) {
#pragma unroll
                for (int i = 0; i < 4; ++i) {
                    partA[w][m * 16 + kg * 4 + i] = s[i];
                    partB[w][m * 16 + kg * 4 + i] = ss[i];
                }
            }
        }
        __syncthreads();
        if (tid < 32) {
            const float s  = partA[0][tid] + partA[1][tid] + partA[2][tid] + partA[3][tid];
            const float ss = partB[0][tid] + partB[1][tid] + partB[2][tid] + partB[3][tid];
            const float mu  = s * (1.f / 512.f);
            const float var = ss * (1.f / 512.f) - mu * mu;
            mu_s[tid] = mu;
            rs_s[tid] = rsqrtf(var + 1e-5f);
        }
        __syncthreads();

        // ---- publish LN'd H (hi/lo bf16) into SM (overwrites Z region)
        {
            float lwv[8], lbv[8];
#pragma unroll
            for (int n = 0; n < 8; ++n) { lwv[n] = lnw[cb1 + n * 16]; lbv[n] = lnb[cb1 + n * 16]; }
#pragma unroll
            for (int m = 0; m < 2; ++m)
#pragma unroll
                for (int n = 0; n < 8; ++n)
#pragma unroll
                    for (int i = 0; i < 4; ++i) {
                        const int t = m * 16 + kg * 4 + i;
                        const float v = (acc[m][n][i] - mu_s[t]) * rs_s[t] * lwv[n] + lbv[n];
                        const u16 h  = bf16_rne(v);
                        const u16 lo = bf16_rne(v - bf16_to_f(h));
                        const int col = cb1 + n * 16;
                        const int idx = (t * 512 + col) ^ SWZ(t);
                        SM[idx] = h;
                        SM[16384 + idx] = lo;
                    }
        }
        __syncthreads();

        // ---- layer 2: q[32 tok x 256] = H[32x512] @ W2, split-bf16
        const int cb2 = w * 64 + lr;
        f32x4 acc2[2][4];
#pragma unroll
        for (int m = 0; m < 2; ++m)
#pragma unroll
            for (int n = 0; n < 4; ++n) acc2[m][n] = (f32x4){0.f, 0.f, 0.f, 0.f};

        for (int k2t = 0; k2t < 16; ++k2t) {
            bf16x8 ah[2], al[2];
#pragma unroll
            for (int m = 0; m < 2; ++m) {
                const int idx = ((m * 16 + lr) * 512 + k2t * 32 + kg * 8) ^ SWZ(lr);
                ah[m] = *(const bf16x8*)&SM[idx];
                al[m] = *(const bf16x8*)&SM[16384 + idx];
            }
            const size_t wb = ((size_t)((k2t * 4 + kg) * 256) + cb2) * 8;
            bf16x8 bh[4], bl[4];
#pragma unroll
            for (int n = 0; n < 4; ++n) bh[n] = *(const bf16x8*)(w2fh + wb + n * 128);
#pragma unroll
            for (int n = 0; n < 4; ++n) bl[n] = *(const bf16x8*)(w2fl + wb + n * 128);
#pragma unroll
            for (int n = 0; n < 4; ++n)
#pragma unroll
                for (int m = 0; m < 2; ++m) acc2[m][n] = __builtin_amdgcn_mfma_f32_16x16x32_bf16(ah[m], bh[n], acc2[m][n], 0, 0, 0);
#pragma unroll
            for (int n = 0; n < 4; ++n)
#pragma unroll
                for (int m = 0; m < 2; ++m) acc2[m][n] = __builtin_amdgcn_mfma_f32_16x16x32_bf16(ah[m], bl[n], acc2[m][n], 0, 0, 0);
#pragma unroll
            for (int n = 0; n < 4; ++n)
#pragma unroll
                for (int m = 0; m < 2; ++m) acc2[m][n] = __builtin_amdgcn_mfma_f32_16x16x32_bf16(al[m], bh[n], acc2[m][n], 0, 0, 0);
        }

        // ---- cosine head
        float b2v[4], prv[4];
#pragma unroll
        for (int n = 0; n < 4; ++n) { b2v[n] = b2[cb2 + n * 16]; prv[n] = prompt[cb2 + n * 16]; }
        {
            float pp = 0.f;
#pragma unroll
            for (int n = 0; n < 4; ++n) pp = fmaf(prv[n], prv[n], pp);
#pragma unroll
            for (int msk = 1; msk < 16; msk <<= 1) pp += __shfl_xor(pp, msk);
            if (l == 0) partP[w] = pp;
        }
#pragma unroll
        for (int m = 0; m < 2; ++m) {
            f32x4 dt = (f32x4){0.f,0.f,0.f,0.f}, nn = (f32x4){0.f,0.f,0.f,0.f};
#pragma unroll
            for (int n = 0; n < 4; ++n)
#pragma unroll
                for (int i = 0; i < 4; ++i) {
                    const float q = acc2[m][n][i] + b2v[n];
                    dt[i] = fmaf(q, prv[n], dt[i]);
                    nn[i] = fmaf(q, q, nn[i]);
                }
#pragma unroll
            for (int msk = 1; msk < 16; msk <<= 1) {
#pragma unroll
                for (int i = 0; i < 4; ++i) { dt[i] += __shfl_xor(dt[i], msk); nn[i] += __shfl_xor(nn[i], msk); }
            }
            if (lr == 0) {
#pragma unroll
                for (int i = 0; i < 4; ++i) {
                    partA[w][m * 16 + kg * 4 + i] = dt[i];
                    partB[w][m * 16 + kg * 4 + i] = nn[i];
                }
            }
        }
        __syncthreads();
        if (tid < 32) {
            const float dot = partA[0][tid] + partA[1][tid] + partA[2][tid] + partA[3][tid];
            const float nq2 = partB[0][tid] + partB[1][tid] + partB[2][tid] + partB[3][tid];
            const float ppt = partP[0] + partP[1] + partP[2] + partP[3];
            const float nq  = fmaxf(sqrtf(nq2), 1e-8f);
            const float npr = fmaxf(sqrtf(ppt), 1e-8f);
            alpha[(size_t)bb * 1024 + t0 + tid] = fmaxf(dot / (nq * npr), 0.f);
        }
    } else {
        // ================= low path: 16 tokens/block, 256 blocks =================
        const int tile = blockIdx.x & 15;
        const int b    = blockIdx.x >> 4;
        const int t0   = tile * 16;

        // ---- stage sp tile: global f32 [s][t] -> LDS bf16 hi/lo [t][s], packed u32 writes
        {
            const int s = tid * 2;               // even s-column
            const float* src0 = sp + ((size_t)b * 512 + s) * 256 + t0;
            const float* src1 = src0 + 256;
#pragma unroll
            for (int j = 0; j < 16; j += 4) {
                const float4 v0 = *(const float4*)(src0 + j);
                const float4 v1 = *(const float4*)(src1 + j);
                const float a0[4] = {v0.x, v0.y, v0.z, v0.w};
                const float a1[4] = {v1.x, v1.y, v1.z, v1.w};
#pragma unroll
                for (int q = 0; q < 4; ++q) {
                    const int t = j + q;
                    uint32_t lp;
                    const uint32_t hp = pack_pair(a0[q], a1[q], lp);
                    const uint32_t idx32 = (uint32_t)(((t * 512 + s) ^ SWZ(t)) >> 1);
                    SM32[idx32]        = hp;
                    SM32[4096 + idx32] = lp;
                }
            }
        }
        __syncthreads();

        // ---- phase A: k_tok[16 x 256] = spT[16x512] @ low_w, split-bf16
        const int cbA = w * 64 + lr;
        f32x4 accA[4];
#pragma unroll
        for (int n = 0; n < 4; ++n) accA[n] = (f32x4){0.f, 0.f, 0.f, 0.f};

        for (int kt = 0; kt < 16; ++kt) {
            const int idx = (lr * 512 + kt * 32 + kg * 8) ^ SWZ(lr);
            const bf16x8 ah = *(const bf16x8*)&SM[idx];
            const bf16x8 al = *(const bf16x8*)&SM[8192 + idx];
            const size_t wb = ((size_t)((kt * 4 + kg) * 256) + cbA) * 8;
            bf16x8 bh[4], bl[4];
#pragma unroll
            for (int n = 0; n < 4; ++n) bh[n] = *(const bf16x8*)(lowfh + wb + n * 128);
#pragma unroll
            for (int n = 0; n < 4; ++n) bl[n] = *(const bf16x8*)(lowfl + wb + n * 128);
#pragma unroll
            for (int n = 0; n < 4; ++n) accA[n] = __builtin_amdgcn_mfma_f32_16x16x32_bf16(ah, bh[n], accA[n], 0, 0, 0);
#pragma unroll
            for (int n = 0; n < 4; ++n) accA[n] = __builtin_amdgcn_mfma_f32_16x16x32_bf16(ah, bl[n], accA[n], 0, 0, 0);
#pragma unroll
            for (int n = 0; n < 4; ++n) accA[n] = __builtin_amdgcn_mfma_f32_16x16x32_bf16(al, bh[n], accA[n], 0, 0, 0);
        }
        __syncthreads();      // all sp reads done

        // ---- publish k_tok (hi/lo bf16) into SM[0..8191]
        {
            float lbv[4];
#pragma unroll
            for (int n = 0; n < 4; ++n) lbv[n] = lb_[cbA + n * 16];
#pragma unroll
            for (int n = 0; n < 4; ++n)
#pragma unroll
                for (int i = 0; i < 4; ++i) {
                    const int t = kg * 4 + i;
                    const float v = accA[n][i] + lbv[n];
                    const u16 h  = bf16_rne(v);
                    const u16 lo = bf16_rne(v - bf16_to_f(h));
                    const int idx = (t * 256 + cbA + n * 16) ^ SWZ(t);
                    SM[idx] = h;
                    SM[4096 + idx] = lo;
                }
        }
        __syncthreads();

        // ---- layer 1: D[16 tok x 512 hid] = K[16x256] @ V1, split-bf16
        const int cb1 = w * 128 + lr;
        f32x4 acc1[8];
#pragma unroll
        for (int n = 0; n < 8; ++n) acc1[n] = (f32x4){0.f, 0.f, 0.f, 0.f};

        for (int kt = 0; kt < 8; ++kt) {
            const int idx = (lr * 256 + kt * 32 + kg * 8) ^ SWZ(lr);
            const bf16x8 ah = *(const bf16x8*)&SM[idx];
            const bf16x8 al = *(const bf16x8*)&SM[4096 + idx];
            const size_t wb = ((size_t)((kt * 4 + kg) * 512) + cb1) * 8;
            bf16x8 bh[8], bl[8];
#pragma unroll
            for (int n = 0; n < 8; ++n) bh[n] = *(const bf16x8*)(v1fh + wb + n * 128);
#pragma unroll
            for (int n = 0; n < 8; ++n) bl[n] = *(const bf16x8*)(v1fl + wb + n * 128);
#pragma unroll
            for (int n = 0; n < 8; ++n) acc1[n] = __builtin_amdgcn_mfma_f32_16x16x32_bf16(ah, bh[n], acc1[n], 0, 0, 0);
#pragma unroll
            for (int n = 0; n < 8; ++n) acc1[n] = __builtin_amdgcn_mfma_f32_16x16x32_bf16(ah, bl[n], acc1[n], 0, 0, 0);
#pragma unroll
            for (int n = 0; n < 8; ++n) acc1[n] = __builtin_amdgcn_mfma_f32_16x16x32_bf16(al, bh[n], acc1[n], 0, 0, 0);
        }

        // ---- + c1, LN stats
        {
            float b1v[8];
#pragma unroll
            for (int n = 0; n < 8; ++n) b1v[n] = c1[cb1 + n * 16];
#pragma unroll
            for (int n = 0; n < 8; ++n)
#pragma unroll
                for (int i = 0; i < 4; ++i) acc1[n][i] += b1v[n];

            f32x4 s = (f32x4){0.f,0.f,0.f,0.f}, ss = (f32x4){0.f,0.f,0.f,0.f};
#pragma unroll
            for (int n = 0; n < 8; ++n)
#pragma unroll
                for (int i = 0; i < 4; ++i) { s[i] += acc1[n][i]; ss[i] = fmaf(acc1[n][i], acc1[n][i], ss[i]); }
#pragma unroll
            for (int msk = 1; msk < 16; msk <<= 1) {
#pragma unroll
                for (int i = 0; i < 4; ++i) { s[i] += __shfl_xor(s[i], msk); ss[i] += __shfl_xor(ss[i], msk); }
            }
            if (lr == 0) {
#pragma unroll
                for (int i = 0; i < 4; ++i) {
                    partA[w][kg * 4 + i] = s[i];
                    partB[w][kg * 4 + i] = ss[i];
                }
            }
        }
        __syncthreads();
        if (tid < 16) {
            const float s  = partA[0][tid] + partA[1][tid] + partA[2][tid] + partA[3][tid];
            const float ss = partB[0][tid] + partB[1][tid] + partB[2][tid] + partB[3][tid];
            const float mu  = s * (1.f / 512.f);
            const float var = ss * (1.f / 512.f) - mu * mu;
            mu_s[tid] = mu;
            rs_s[tid] = rsqrtf(var + 1e-5f);
        }
        __syncthreads();

        // ---- publish LN'd H (hi/lo bf16) into SM (overwrites k_tok)
        {
            float lwv[8], lbv[8];
#pragma unroll
            for (int n = 0; n < 8; ++n) { lwv[n] = vlnw[cb1 + n * 16]; lbv[n] = vlnb[cb1 + n * 16]; }
#pragma unroll
            for (int n = 0; n < 8; ++n)
#pragma unroll
                for (int i = 0; i < 4; ++i) {
                    const int t = kg * 4 + i;
                    const float v = (acc1[n][i] - mu_s[t]) * rs_s[t] * lwv[n] + lbv[n];
                    const u16 h  = bf16_rne(v);
                    const u16 lo = bf16_rne(v - bf16_to_f(h));
                    const int idx = (t * 512 + cb1 + n * 16) ^ SWZ(t);
                    SM[idx] = h;
                    SM[8192 + idx] = lo;
                }
        }
        __syncthreads();

        // ---- layer 2 + sigmoid -> gate
        const int cb2 = w * 64 + lr;
        f32x4 acc2[4];
#pragma unroll
        for (int n = 0; n < 4; ++n) acc2[n] = (f32x4){0.f, 0.f, 0.f, 0.f};

        for (int k2t = 0; k2t < 16; ++k2t) {
            const int idx = (lr * 512 + k2t * 32 + kg * 8) ^ SWZ(lr);
            const bf16x8 ah = *(const bf16x8*)&SM[idx];
            const bf16x8 al = *(const bf16x8*)&SM[8192 + idx];
            const size_t wb = ((size_t)((k2t * 4 + kg) * 256) + cb2) * 8;
            bf16x8 bh[4], bl[4];
#pragma unroll
            for (int n = 0; n < 4; ++n) bh[n] = *(const bf16x8*)(v2fh + wb + n * 128);
#pragma unroll
            for (int n = 0; n < 4; ++n) bl[n] = *(const bf16x8*)(v2fl + wb + n * 128);
#pragma unroll
            for (int n = 0; n < 4; ++n) acc2[n] = __builtin_amdgcn_mfma_f32_16x16x32_bf16(ah, bh[n], acc2[n], 0, 0, 0);
#pragma unroll
            for (int n = 0; n < 4; ++n) acc2[n] = __builtin_amdgcn_mfma_f32_16x16x32_bf16(ah, bl[n], acc2[n], 0, 0, 0);
#pragma unroll
            for (int n = 0; n < 4; ++n) acc2[n] = __builtin_amdgcn_mfma_f32_16x16x32_bf16(al, bh[n], acc2[n], 0, 0, 0);
        }
        {
#pragma unroll
            for (int n = 0; n < 4; ++n) {
                const float b2v = c2[cb2 + n * 16];
                float4 o;
                o.x = 1.f / (1.f + expf(-(acc2[n][0] + b2v)));
                o.y = 1.f / (1.f + expf(-(acc2[n][1] + b2v)));
                o.z = 1.f / (1.f + expf(-(acc2[n][2] + b2v)));
                o.w = 1.f / (1.f + expf(-(acc2[n][3] + b2v)));
                *(float4*)&gate[((size_t)b * 256 + cb2 + n * 16) * 256 + t0 + kg * 4] = o;
            }
        }
    }
}

// ---------------------------------------------------------------- K_final: apply alpha/gate + inverse Haar
__global__ __launch_bounds__(256)
void k_final(const float* __restrict__ xb,
             const float* __restrict__ alpha,
             const float* __restrict__ gate,
             float* __restrict__ out)
{
    const int bc    = blockIdx.x >> 3;
    const int ytile = blockIdx.x & 7;
    const int x2 = threadIdx.x & 31;
    const int y  = ytile * 8 + (threadIdx.x >> 5);
    const int b  = bc >> 8;

    const float* p = xb + (size_t)bc * (128 * 128) + (2 * y) * 128 + 4 * x2;
    const float4 r0 = *(const float4*)(p);
    const float4 r1 = *(const float4*)(p + 128);

    const int th = (y >> 1) * 32 + x2;
    const float ah = alpha[(size_t)0 * 16384 + b * 1024 + th];
    const float av = alpha[(size_t)1 * 16384 + b * 1024 + th];
    const float ad = alpha[(size_t)2 * 16384 + b * 1024 + th];
    const float g  = gate[(size_t)bc * 256 + (y >> 2) * 16 + (x2 >> 1)];

    float4 o_top, o_bot;
    {
        const float p00 = r0.x, p01 = r0.y, p10 = r1.x, p11 = r1.y;
        const float a  = 0.25f * (p00 + p01 + p10 + p11) * g;
        const float hb = 0.25f * (p00 - p01 + p10 - p11) * ah;
        const float vb = 0.25f * (p00 + p01 - p10 - p11) * av;
        const float db = 0.25f * (p00 - p01 - p10 + p11) * ad;
        o_top.x = a + hb + vb + db;  o_top.y = a - hb + vb - db;
        o_bot.x = a + hb - vb - db;  o_bot.y = a - hb - vb + db;
    }
    {
        const float p00 = r0.z, p01 = r0.w, p10 = r1.z, p11 = r1.w;
        const float a  = 0.25f * (p00 + p01 + p10 + p11) * g;
        const float hb = 0.25f * (p00 - p01 + p10 - p11) * ah;
        const float vb = 0.25f * (p00 + p01 - p10 - p11) * av;
        const float db = 0.25f * (p00 - p01 - p10 + p11) * ad;
        o_top.z = a + hb + vb + db;  o_top.w = a - hb + vb - db;
        o_bot.z = a + hb - vb - db;  o_bot.w = a - hb - vb + db;
    }
    float* q = out + (size_t)bc * (128 * 128) + (2 * y) * 128 + 4 * x2;
    *(float4*)(q)       = o_top;
    *(float4*)(q + 128) = o_bot;
}

// ---------------------------------------------------------------- launch
extern "C" void kernel_launch(void* const* d_in, const int* in_sizes, int n_in,
                              void* d_out, int out_size, void* d_ws, size_t ws_size,
                              hipStream_t stream)
{
    (void)in_sizes; (void)n_in; (void)out_size; (void)ws_size;
    const float* x_big     = (const float*)d_in[0];
    const float* x_small   = (const float*)d_in[1];
    const float* hf_w1     = (const float*)d_in[2];
    const float* hf_b1     = (const float*)d_in[3];
    const float* hf_ln_w   = (const float*)d_in[4];
    const float* hf_ln_b   = (const float*)d_in[5];
    const float* hf_w2     = (const float*)d_in[6];
    const float* hf_b2     = (const float*)d_in[7];
    const float* hf_prompt = (const float*)d_in[8];
    const float* low_w     = (const float*)d_in[9];
    const float* low_b     = (const float*)d_in[10];
    const float* lf_w1     = (const float*)d_in[11];
    const float* lf_b1     = (const float*)d_in[12];
    const float* lf_ln_w   = (const float*)d_in[13];
    const float* lf_ln_b   = (const float*)d_in[14];
    const float* lf_w2     = (const float*)d_in[15];
    const float* lf_b2     = (const float*)d_in[16];
    float* out = (float*)d_out;

    float* ws    = (float*)d_ws;
    float* z     = ws;                               // 3*4096*1024   = 12,582,912 f
    float* sp    = z + (size_t)3 * 4096 * 1024;      // 16*512*256    =  2,097,152 f
    float* alpha = sp + (size_t)16 * 512 * 256;      // 3*16*1024     =     49,152 f
    float* gate  = alpha + (size_t)3 * 16 * 1024;    // 16*256*256    =  1,048,576 f
    u16* w1fh  = (u16*)(gate + (size_t)16 * 256 * 256);  // 131072 u16 each
    u16* w1fl  = w1fh  + 131072;
    u16* w2fh  = w1fl  + 131072;
    u16* w2fl  = w2fh  + 131072;
    u16* lowfh = w2fl  + 131072;
    u16* lowfl = lowfh + 131072;
    u16* lw1fh = lowfl + 131072;
    u16* lw1fl = lw1fh + 131072;
    u16* lw2fh = lw1fl + 131072;
    u16* lw2fl = lw2fh + 131072;

    k_front<<<14336, 256, 0, stream>>>(x_big, x_small,
                                       hf_w1, hf_w2, low_w, lf_w1, lf_w2,
                                       z, sp,
                                       w1fh, w1fl, w2fh, w2fl,
                                       lowfh, lowfl, lw1fh, lw1fl, lw2fh, lw2fl);
    k_mlp  <<<1792, 256, 0, stream>>>(z, sp,
                                      w1fh, w1fl, w2fh, w2fl,
                                      hf_b1, hf_ln_w, hf_ln_b, hf_b2, hf_prompt,
                                      lowfh, lowfl, low_b,
                                      lw1fh, lw1fl, lf_b1, lf_ln_w, lf_ln_b,
                                      lw2fh, lw2fl, lf_b2,
                                      alpha, gate);
    k_final<<<32768, 256, 0, stream>>>(x_big, alpha, gate, out);
}